// Round 1
// baseline (9116.511 us; speedup 1.0000x reference)
//
#include <hip/hip_runtime.h>
#include <math.h>

#define DM    1024
#define NH    16
#define DH    64
#define NL    6
#define DFF   4096
#define QLEN  512
#define MLEN  128
#define B_    4
#define KL    640
#define CLAMP 512
#define EPS   1e-5f

// ---------------- block-wide sum over 256 threads (4 waves) ----------------
__device__ __forceinline__ float block_sum(float v, float* sm4) {
#pragma unroll
  for (int o = 32; o > 0; o >>= 1) v += __shfl_down(v, o, 64);
  int lane = threadIdx.x & 63, wid = threadIdx.x >> 6;
  if (lane == 0) sm4[wid] = v;
  __syncthreads();
  float r = sm4[0] + sm4[1] + sm4[2] + sm4[3];
  __syncthreads();
  return r;
}

// ---------------- sinusoidal relative position embedding ----------------
__global__ __launch_bounds__(256) void pos_emb_kernel(float* __restrict__ pe) {
  int p = blockIdx.x;                       // 0..KL-1
  float pos = fminf((float)(KL - 1 - p), (float)CLAMP);
  for (int f = threadIdx.x; f < 512; f += 256) {
    float inv = powf(10000.0f, -(float)f * (1.0f / 512.0f));
    float a = pos * inv;
    pe[(size_t)p * DM + f]       = sinf(a);
    pe[(size_t)p * DM + 512 + f] = cosf(a);
  }
}

// ---------------- LayerNorm over D=1024; optional 2-source concat ----------------
// row < rows0 -> src0[row], else src1[row-rows0]
__global__ __launch_bounds__(256) void ln_kernel(
    const float* __restrict__ src0, const float* __restrict__ src1,
    const float* __restrict__ g, const float* __restrict__ b,
    float* __restrict__ out, int rows0) {
  __shared__ float sm4[4];
  int row = blockIdx.x;
  const float* src = (row < rows0) ? (src0 + (size_t)row * DM)
                                   : (src1 + (size_t)(row - rows0) * DM);
  float4 v = ((const float4*)src)[threadIdx.x];
  float mean = block_sum(v.x + v.y + v.z + v.w, sm4) * (1.0f / DM);
  float dx = v.x - mean, dy = v.y - mean, dz = v.z - mean, dw = v.w - mean;
  float var = block_sum(dx * dx + dy * dy + dz * dz + dw * dw, sm4) * (1.0f / DM);
  float rstd = rsqrtf(var + EPS);
  float4 gg = ((const float4*)g)[threadIdx.x];
  float4 bb = ((const float4*)b)[threadIdx.x];
  float4 o;
  o.x = dx * rstd * gg.x + bb.x;
  o.y = dy * rstd * gg.y + bb.y;
  o.z = dz * rstd * gg.z + bb.z;
  o.w = dw * rstd * gg.w + bb.w;
  ((float4*)(out + (size_t)row * DM))[threadIdx.x] = o;
}

// ---------------- fp32 GEMM: C[m,n] = sum_k A[m,k]*B[n,k] (+bias)(relu)(+resid) ----------------
// 64x64 tile, 16x16 threads, 4x4 per thread, BK=16
template <int BIAS, int RELU, int RESID>
__global__ __launch_bounds__(256) void gemm_bt(
    const float* __restrict__ A, const float* __restrict__ Bm,
    const float* __restrict__ bias, const float* __restrict__ resid,
    float* __restrict__ C, int M, int N, int K) {
  __shared__ float As[16][65], Bs[16][65];
  int t = threadIdx.x;
  int tx = t & 15, ty = t >> 4;
  int m0 = blockIdx.y * 64, n0 = blockIdx.x * 64;
  int lr = t >> 2, lc = (t & 3) * 4;
  const float* Ap = A + (size_t)(m0 + lr) * K + lc;
  const float* Bp = Bm + (size_t)(n0 + lr) * K + lc;
  float acc[4][4] = {};
  for (int k0 = 0; k0 < K; k0 += 16) {
    float4 avv = *(const float4*)(Ap + k0);
    float4 bvv = *(const float4*)(Bp + k0);
    __syncthreads();
    As[lc + 0][lr] = avv.x; As[lc + 1][lr] = avv.y;
    As[lc + 2][lr] = avv.z; As[lc + 3][lr] = avv.w;
    Bs[lc + 0][lr] = bvv.x; Bs[lc + 1][lr] = bvv.y;
    Bs[lc + 2][lr] = bvv.z; Bs[lc + 3][lr] = bvv.w;
    __syncthreads();
#pragma unroll
    for (int kk = 0; kk < 16; ++kk) {
      float a0 = As[kk][ty * 4 + 0], a1 = As[kk][ty * 4 + 1];
      float a2 = As[kk][ty * 4 + 2], a3 = As[kk][ty * 4 + 3];
      float b0 = Bs[kk][tx * 4 + 0], b1 = Bs[kk][tx * 4 + 1];
      float b2 = Bs[kk][tx * 4 + 2], b3 = Bs[kk][tx * 4 + 3];
      acc[0][0] += a0 * b0; acc[0][1] += a0 * b1; acc[0][2] += a0 * b2; acc[0][3] += a0 * b3;
      acc[1][0] += a1 * b0; acc[1][1] += a1 * b1; acc[1][2] += a1 * b2; acc[1][3] += a1 * b3;
      acc[2][0] += a2 * b0; acc[2][1] += a2 * b1; acc[2][2] += a2 * b2; acc[2][3] += a2 * b3;
      acc[3][0] += a3 * b0; acc[3][1] += a3 * b1; acc[3][2] += a3 * b2; acc[3][3] += a3 * b3;
    }
  }
#pragma unroll
  for (int i = 0; i < 4; ++i) {
    int m = m0 + ty * 4 + i;
#pragma unroll
    for (int j = 0; j < 4; ++j) {
      int n = n0 + tx * 4 + j;
      float v = acc[i][j];
      if (BIAS) v += bias[n];
      if (RELU) v = fmaxf(v, 0.0f);
      if (RESID) v += resid[(size_t)m * N + n];
      C[(size_t)m * N + n] = v;
    }
  }
}

// ---------------- flash-style relative attention ----------------
// grid (8 q-tiles, 16 heads, 4 batch); block 256 = 16x16, 4x4 per thread
// S[i,j] = (q_i+rwb)·k_j + (q_i+rrb)·r[j+511-i]; mask j > i+128; softmax over j; O = P·V
__global__ __launch_bounds__(256) void attn_kernel(
    const float* __restrict__ wh,   // (KL*B_, 3072) qkv projections
    const float* __restrict__ rk,   // (KL, 1024)  r_head_k
    const float* __restrict__ rwb,  // (16,64)
    const float* __restrict__ rrb,  // (16,64)
    float* __restrict__ av) {       // (QLEN, B_, 1024)
  __shared__ float qws[16][65], qrs[16][65], ks[16][65], rs[16][132];
  __shared__ float ps[64][65], vs[64][65];
  int i0 = blockIdx.x * 64;
  int n = blockIdx.y, b = blockIdx.z;
  int t = threadIdx.x, tx = t & 15, ty = t >> 4;

  float o[4][4] = {};
  float mrun[4], lrun[4];
#pragma unroll
  for (int i = 0; i < 4; ++i) { mrun[i] = -INFINITY; lrun[i] = 0.0f; }

  int jend = i0 + 192; if (jend > KL) jend = KL;
  int lr = t >> 2, lc = (t & 3) * 4;   // 64 rows x 16 cols loads
  int lr2 = t >> 1, lc2 = (t & 1) * 8; // 128 rows x 16 cols loads

  for (int j0 = 0; j0 < jend; j0 += 64) {
    float s[4][4] = {};
    int m0r = j0 - i0 + 448;  // base r-row for this tile pair
    for (int dk = 0; dk < 64; dk += 16) {
      float4 qv = *(const float4*)(wh + ((size_t)(i0 + lr + MLEN) * B_ + b) * 3072 + n * 64 + dk + lc);
      float4 kv = *(const float4*)(wh + ((size_t)(j0 + lr) * B_ + b) * 3072 + 1024 + n * 64 + dk + lc);
      float4 wb = *(const float4*)(rwb + n * 64 + dk + lc);
      float4 rb = *(const float4*)(rrb + n * 64 + dk + lc);
      int mrow = m0r + lr2; if (mrow > KL - 1) mrow = KL - 1;  // clamped rows are masked anyway
      const float* rp = rk + (size_t)mrow * DM + n * 64 + dk + lc2;
      float4 r0 = *(const float4*)rp;
      float4 r1 = *(const float4*)(rp + 4);
      __syncthreads();
      qws[lc + 0][lr] = qv.x + wb.x; qws[lc + 1][lr] = qv.y + wb.y;
      qws[lc + 2][lr] = qv.z + wb.z; qws[lc + 3][lr] = qv.w + wb.w;
      qrs[lc + 0][lr] = qv.x + rb.x; qrs[lc + 1][lr] = qv.y + rb.y;
      qrs[lc + 2][lr] = qv.z + rb.z; qrs[lc + 3][lr] = qv.w + rb.w;
      ks[lc + 0][lr] = kv.x; ks[lc + 1][lr] = kv.y;
      ks[lc + 2][lr] = kv.z; ks[lc + 3][lr] = kv.w;
      rs[lc2 + 0][lr2] = r0.x; rs[lc2 + 1][lr2] = r0.y;
      rs[lc2 + 2][lr2] = r0.z; rs[lc2 + 3][lr2] = r0.w;
      rs[lc2 + 4][lr2] = r1.x; rs[lc2 + 5][lr2] = r1.y;
      rs[lc2 + 6][lr2] = r1.z; rs[lc2 + 7][lr2] = r1.w;
      __syncthreads();
#pragma unroll
      for (int kk = 0; kk < 16; ++kk) {
        float aw[4], ar[4], bk[4];
#pragma unroll
        for (int i = 0; i < 4; ++i) { aw[i] = qws[kk][ty * 4 + i]; ar[i] = qrs[kk][ty * 4 + i]; }
#pragma unroll
        for (int j = 0; j < 4; ++j) bk[j] = ks[kk][tx * 4 + j];
#pragma unroll
        for (int i = 0; i < 4; ++i)
#pragma unroll
          for (int j = 0; j < 4; ++j)
            s[i][j] += aw[i] * bk[j] + ar[i] * rs[kk][(tx * 4 + j) - (ty * 4 + i) + 63];
      }
    }
    // scale + mask + online softmax (rows owned by same-ty 16-lane groups)
    float fac[4], p[4][4];
#pragma unroll
    for (int i = 0; i < 4; ++i) {
      int gi = i0 + ty * 4 + i;
      float mx = -INFINITY;
#pragma unroll
      for (int j = 0; j < 4; ++j) {
        int gj = j0 + tx * 4 + j;
        s[i][j] = (gj > gi + MLEN) ? -INFINITY : s[i][j] * 0.125f;
        mx = fmaxf(mx, s[i][j]);
      }
#pragma unroll
      for (int o_ = 1; o_ < 16; o_ <<= 1) mx = fmaxf(mx, __shfl_xor(mx, o_, 64));
      float mnew = fmaxf(mrun[i], mx);
      fac[i] = expf(mrun[i] - mnew);
      float sum = 0.0f;
#pragma unroll
      for (int j = 0; j < 4; ++j) { p[i][j] = expf(s[i][j] - mnew); sum += p[i][j]; }
#pragma unroll
      for (int o_ = 1; o_ < 16; o_ <<= 1) sum += __shfl_xor(sum, o_, 64);
      lrun[i] = lrun[i] * fac[i] + sum;
      mrun[i] = mnew;
    }
    __syncthreads();  // prev PV reads of ps/vs complete
#pragma unroll
    for (int i = 0; i < 4; ++i)
#pragma unroll
      for (int j = 0; j < 4; ++j)
        ps[ty * 4 + i][tx * 4 + j] = p[i][j];
#pragma unroll
    for (int it = 0; it < 4; ++it) {
      int vr = (t >> 4) + it * 16, vc = (t & 15) * 4;
      float4 vv = *(const float4*)(wh + ((size_t)(j0 + vr) * B_ + b) * 3072 + 2048 + n * 64 + vc);
      vs[vr][vc + 0] = vv.x; vs[vr][vc + 1] = vv.y;
      vs[vr][vc + 2] = vv.z; vs[vr][vc + 3] = vv.w;
    }
    __syncthreads();
#pragma unroll
    for (int i = 0; i < 4; ++i)
#pragma unroll
      for (int d = 0; d < 4; ++d)
        o[i][d] *= fac[i];
    for (int kk = 0; kk < 64; ++kk) {
      float pv[4], vvv[4];
#pragma unroll
      for (int i = 0; i < 4; ++i) pv[i] = ps[ty * 4 + i][kk];
#pragma unroll
      for (int d = 0; d < 4; ++d) vvv[d] = vs[kk][tx * 4 + d];
#pragma unroll
      for (int i = 0; i < 4; ++i)
#pragma unroll
        for (int d = 0; d < 4; ++d)
          o[i][d] += pv[i] * vvv[d];
    }
  }
#pragma unroll
  for (int i = 0; i < 4; ++i) {
    float inv = 1.0f / lrun[i];
#pragma unroll
    for (int d = 0; d < 4; ++d)
      av[((size_t)(i0 + ty * 4 + i) * B_ + b) * DM + n * 64 + tx * 4 + d] = o[i][d] * inv;
  }
}

// ---------------- host ----------------
extern "C" void kernel_launch(void* const* d_in, const int* in_sizes, int n_in,
                              void* d_out, int out_size, void* d_ws, size_t ws_size,
                              hipStream_t stream) {
  const float* inputs = (const float*)d_in[0];
  const float* mems   = (const float*)d_in[1];
  const float* rwb    = (const float*)d_in[2];
  const float* rrb    = (const float*)d_in[3];
  const float* qkv_w  = (const float*)d_in[4];
  const float* r_w    = (const float*)d_in[5];
  const float* o_w    = (const float*)d_in[6];
  const float* ln1_g  = (const float*)d_in[7];
  const float* ln1_b  = (const float*)d_in[8];
  const float* ff_w1  = (const float*)d_in[9];
  const float* ff_b1  = (const float*)d_in[10];
  const float* ff_w2  = (const float*)d_in[11];
  const float* ff_b2  = (const float*)d_in[12];
  const float* ln2_g  = (const float*)d_in[13];
  const float* ln2_b  = (const float*)d_in[14];
  const float* fin_g  = (const float*)d_in[15];
  const float* fin_b  = (const float*)d_in[16];
  float* out = (float*)d_out;

  float* ws   = (float*)d_ws;
  float* xbuf = ws;                        // 512*4*1024      = 2,097,152
  float* pe   = xbuf + 2097152;            // 640*1024        =   655,360
  float* h    = pe + 655360;               // 2560*1024       = 2,621,440
  float* wh   = h + 2621440;               // 2560*3072       = 7,864,320
  float* rk   = wh + 7864320;              // 640*1024        =   655,360
  float* av   = rk + 655360;               // 512*4*1024      = 2,097,152
  float* ffh  = av + 2097152;              // 2048*4096       = 8,388,608

  pos_emb_kernel<<<KL, 256, 0, stream>>>(pe);

  const float* xcur = inputs;
  for (int l = 0; l < NL; ++l) {
    // LN over [mems_l ; x]  -> h (2560 rows)
    ln_kernel<<<KL * B_, 256, 0, stream>>>(
        mems + (size_t)l * MLEN * B_ * DM, xcur,
        ln1_g + l * DM, ln1_b + l * DM, h, MLEN * B_);
    // QKV projection: (2560,1024)x(3072,1024)^T
    gemm_bt<0, 0, 0><<<dim3(3072 / 64, 2560 / 64), 256, 0, stream>>>(
        h, qkv_w + (size_t)l * 3072 * DM, nullptr, nullptr, wh, 2560, 3072, DM);
    // r_head_k: (640,1024)x(1024,1024)^T
    gemm_bt<0, 0, 0><<<dim3(DM / 64, KL / 64), 256, 0, stream>>>(
        pe, r_w + (size_t)l * DM * DM, nullptr, nullptr, rk, KL, DM, DM);
    // attention -> av
    attn_kernel<<<dim3(QLEN / 64, NH, B_), 256, 0, stream>>>(wh, rk, rwb, rrb, av);
    // out projection + residual -> xbuf
    gemm_bt<0, 0, 1><<<dim3(DM / 64, (QLEN * B_) / 64), 256, 0, stream>>>(
        av, o_w + (size_t)l * DM * DM, nullptr, xcur, xbuf, QLEN * B_, DM, DM);
    // FFN
    ln_kernel<<<QLEN * B_, 256, 0, stream>>>(
        xbuf, nullptr, ln2_g + l * DM, ln2_b + l * DM, h, 1 << 30);
    gemm_bt<1, 1, 0><<<dim3(DFF / 64, (QLEN * B_) / 64), 256, 0, stream>>>(
        h, ff_w1 + (size_t)l * DFF * DM, ff_b1 + (size_t)l * DFF, nullptr, ffh,
        QLEN * B_, DFF, DM);
    gemm_bt<1, 0, 1><<<dim3(DM / 64, (QLEN * B_) / 64), 256, 0, stream>>>(
        ffh, ff_w2 + (size_t)l * DM * DFF, ff_b2 + (size_t)l * DM, xbuf, xbuf,
        QLEN * B_, DM, DFF);
    xcur = xbuf;
  }
  // final LN -> out
  ln_kernel<<<QLEN * B_, 256, 0, stream>>>(xbuf, nullptr, fin_g, fin_b, out, 1 << 30);
}

// Round 3
// 3237.035 us; speedup vs baseline: 2.8163x; 2.8163x over previous
//
#include <hip/hip_runtime.h>
#include <math.h>
#include <stdint.h>

#define DM    1024
#define NH    16
#define DH    64
#define NL    6
#define DFF   4096
#define QLEN  512
#define MLEN  128
#define B_    4
#define KL    640
#define CLAMP 512
#define EPS   1e-5f

typedef _Float16 f16x8 __attribute__((ext_vector_type(8)));
typedef _Float16 f16x4 __attribute__((ext_vector_type(4)));
typedef float    f32x4 __attribute__((ext_vector_type(4)));

// ---- async global->LDS, 16B per lane; LDS base must be wave-uniform ----
__device__ __forceinline__ void gload16(const void* g, void* l) {
  __builtin_amdgcn_global_load_lds(
      (const __attribute__((address_space(1))) void*)g,
      (__attribute__((address_space(3))) void*)l, 16, 0, 0);
}

// ---------------- block-wide sum over 256 threads (4 waves) ----------------
__device__ __forceinline__ float block_sum(float v, float* sm4) {
#pragma unroll
  for (int o = 32; o > 0; o >>= 1) v += __shfl_down(v, o, 64);
  int lane = threadIdx.x & 63, wid = threadIdx.x >> 6;
  if (lane == 0) sm4[wid] = v;
  __syncthreads();
  float r = sm4[0] + sm4[1] + sm4[2] + sm4[3];
  __syncthreads();
  return r;
}

// ---------------- sinusoidal relative position embedding (f16 out) ----------------
__global__ __launch_bounds__(256) void pos_emb_kernel(_Float16* __restrict__ pe) {
  int p = blockIdx.x;                       // 0..KL-1
  float pos = fminf((float)(KL - 1 - p), (float)CLAMP);
  for (int f = threadIdx.x; f < 512; f += 256) {
    float inv = powf(10000.0f, -(float)f * (1.0f / 512.0f));
    float a = pos * inv;
    pe[(size_t)p * DM + f]       = (_Float16)sinf(a);
    pe[(size_t)p * DM + 512 + f] = (_Float16)cosf(a);
  }
}

// ---------------- weight cast fp32 -> f16, one layer's 5 weights ----------------
// segments: qkv 3145728 | r_w 1048576 | o_w 1048576 | ff1 4194304 | ff2 4194304
__global__ __launch_bounds__(256) void cast_w_kernel(
    const float* __restrict__ s0, const float* __restrict__ s1,
    const float* __restrict__ s2, const float* __restrict__ s3,
    const float* __restrict__ s4, _Float16* __restrict__ dst) {
  size_t i = ((size_t)blockIdx.x * 256 + threadIdx.x) * 4;
  const float* src; size_t off;
  if (i < 3145728)      { src = s0; off = 0; }
  else if (i < 4194304) { src = s1; off = 3145728; }
  else if (i < 5242880) { src = s2; off = 4194304; }
  else if (i < 9437184) { src = s3; off = 5242880; }
  else                  { src = s4; off = 9437184; }
  float4 v = *(const float4*)(src + (i - off));
  f16x4 o = { (_Float16)v.x, (_Float16)v.y, (_Float16)v.z, (_Float16)v.w };
  *(f16x4*)(dst + i) = o;
}

// ---------------- LayerNorm over D=1024; optional 2-source concat ----------------
template <int OUTF16>
__global__ __launch_bounds__(256) void ln_kernel(
    const float* __restrict__ src0, const float* __restrict__ src1,
    const float* __restrict__ g, const float* __restrict__ b,
    float* __restrict__ outf, _Float16* __restrict__ outh, int rows0) {
  __shared__ float sm4[4];
  int row = blockIdx.x;
  const float* src = (row < rows0) ? (src0 + (size_t)row * DM)
                                   : (src1 + (size_t)(row - rows0) * DM);
  float4 v = ((const float4*)src)[threadIdx.x];
  float mean = block_sum(v.x + v.y + v.z + v.w, sm4) * (1.0f / DM);
  float dx = v.x - mean, dy = v.y - mean, dz = v.z - mean, dw = v.w - mean;
  float var = block_sum(dx * dx + dy * dy + dz * dz + dw * dw, sm4) * (1.0f / DM);
  float rstd = rsqrtf(var + EPS);
  float4 gg = ((const float4*)g)[threadIdx.x];
  float4 bb = ((const float4*)b)[threadIdx.x];
  float ox = dx * rstd * gg.x + bb.x;
  float oy = dy * rstd * gg.y + bb.y;
  float oz = dz * rstd * gg.z + bb.z;
  float ow = dw * rstd * gg.w + bb.w;
  if (OUTF16) {
    f16x4 o = { (_Float16)ox, (_Float16)oy, (_Float16)oz, (_Float16)ow };
    *(f16x4*)(outh + (size_t)row * DM + threadIdx.x * 4) = o;
  } else {
    float4 o = { ox, oy, oz, ow };
    ((float4*)(outf + (size_t)row * DM))[threadIdx.x] = o;
  }
}

// ---------------- f16 MFMA GEMM: C[m,n] = sum_k A[m,k]*B[n,k] ----------------
// 128x128 tile, BK=32, 256 threads (4 waves, 2x2 of 64x64), global_load_lds staging
template <int BIAS, int RELU, int RESID, int OUTF16>
__global__ __launch_bounds__(256) void gemm_mfma(
    const _Float16* __restrict__ A, const _Float16* __restrict__ B,
    const float* __restrict__ bias, const float* __restrict__ resid,
    float* __restrict__ Cf, _Float16* __restrict__ Ch,
    int M, int N, int K) {
  __shared__ alignas(16) _Float16 As[128 * 32];
  __shared__ alignas(16) _Float16 Bs[128 * 32];
  const int t = threadIdx.x;
  const int lane = t & 63, wid = t >> 6;
  const int m0 = blockIdx.y * 128, n0 = blockIdx.x * 128;
  const int wm = (wid >> 1) * 64, wn = (wid & 1) * 64;

  // staging: tile = 128 rows x 32 k of f16 = 8KB = 512 x 16B chunks.
  // instr i (0..7) covers chunks [i*64, i*64+64), LDS bytes [i*1024, ..).
  // wave wid issues i = wid and i = wid+4; chunk c -> row c>>2, k-chunk c&3.
  const int c0 = wid * 64 + lane, c1 = c0 + 256;
  const _Float16* Ap0 = A + (size_t)(m0 + (c0 >> 2)) * K + (c0 & 3) * 8;
  const _Float16* Ap1 = A + (size_t)(m0 + (c1 >> 2)) * K + (c1 & 3) * 8;
  const _Float16* Bp0 = B + (size_t)(n0 + (c0 >> 2)) * K + (c0 & 3) * 8;
  const _Float16* Bp1 = B + (size_t)(n0 + (c1 >> 2)) * K + (c1 & 3) * 8;
  _Float16* Asw0 = &As[wid * 512];
  _Float16* Asw1 = &As[wid * 512 + 2048];
  _Float16* Bsw0 = &Bs[wid * 512];
  _Float16* Bsw1 = &Bs[wid * 512 + 2048];

  f32x4 acc[4][4] = {};
  for (int k0 = 0; k0 < K; k0 += 32) {
    __syncthreads();               // prior ds_reads done before overwrite
    gload16(Ap0 + k0, Asw0);
    gload16(Ap1 + k0, Asw1);
    gload16(Bp0 + k0, Bsw0);
    gload16(Bp1 + k0, Bsw1);
    __syncthreads();               // vmcnt(0) drained by compiler before barrier
    f16x8 af[4], bf[4];
#pragma unroll
    for (int f = 0; f < 4; ++f) {
      af[f] = *(const f16x8*)&As[(wm + f * 16 + (lane & 15)) * 32 + (lane >> 4) * 8];
      bf[f] = *(const f16x8*)&Bs[(wn + f * 16 + (lane & 15)) * 32 + (lane >> 4) * 8];
    }
#pragma unroll
    for (int i = 0; i < 4; ++i)
#pragma unroll
      for (int j = 0; j < 4; ++j)
        acc[i][j] = __builtin_amdgcn_mfma_f32_16x16x32_f16(af[i], bf[j], acc[i][j], 0, 0, 0);
  }
  // epilogue: C/D layout col=lane&15, row=(lane>>4)*4+reg
#pragma unroll
  for (int i = 0; i < 4; ++i) {
#pragma unroll
    for (int j = 0; j < 4; ++j) {
      const int n = n0 + wn + j * 16 + (lane & 15);
      float bv = 0.0f;
      if (BIAS) bv = bias[n];
#pragma unroll
      for (int r = 0; r < 4; ++r) {
        const int m = m0 + wm + i * 16 + (lane >> 4) * 4 + r;
        float v = acc[i][j][r] + bv;
        if (RELU) v = fmaxf(v, 0.0f);
        if (RESID) v += resid[(size_t)m * N + n];
        if (OUTF16) Ch[(size_t)m * N + n] = (_Float16)v;
        else        Cf[(size_t)m * N + n] = v;
      }
    }
  }
}

// ---------------- flash-style relative attention (fp32; f16 output) ----------------
__global__ __launch_bounds__(256) void attn_kernel(
    const float* __restrict__ wh,   // (KL*B_, 3072) qkv projections
    const float* __restrict__ rk,   // (KL, 1024)  r_head_k
    const float* __restrict__ rwb,  // (16,64)
    const float* __restrict__ rrb,  // (16,64)
    _Float16* __restrict__ av) {    // (QLEN, B_, 1024) f16
  __shared__ float qws[16][65], qrs[16][65], ks[16][65], rs[16][132];
  __shared__ float ps[64][65], vs[64][65];
  int i0 = blockIdx.x * 64;
  int n = blockIdx.y, b = blockIdx.z;
  int t = threadIdx.x, tx = t & 15, ty = t >> 4;

  float o[4][4] = {};
  float mrun[4], lrun[4];
#pragma unroll
  for (int i = 0; i < 4; ++i) { mrun[i] = -INFINITY; lrun[i] = 0.0f; }

  int jend = i0 + 192; if (jend > KL) jend = KL;
  int lr = t >> 2, lc = (t & 3) * 4;   // 64 rows x 16 cols loads
  int lr2 = t >> 1, lc2 = (t & 1) * 8; // 128 rows x 16 cols loads

  for (int j0 = 0; j0 < jend; j0 += 64) {
    float s[4][4] = {};
    int m0r = j0 - i0 + 448;  // base r-row for this tile pair
    for (int dk = 0; dk < 64; dk += 16) {
      float4 qv = *(const float4*)(wh + ((size_t)(i0 + lr + MLEN) * B_ + b) * 3072 + n * 64 + dk + lc);
      float4 kv = *(const float4*)(wh + ((size_t)(j0 + lr) * B_ + b) * 3072 + 1024 + n * 64 + dk + lc);
      float4 wb = *(const float4*)(rwb + n * 64 + dk + lc);
      float4 rb = *(const float4*)(rrb + n * 64 + dk + lc);
      int mrow = m0r + lr2; if (mrow > KL - 1) mrow = KL - 1;  // clamped rows are masked anyway
      const float* rp = rk + (size_t)mrow * DM + n * 64 + dk + lc2;
      float4 r0 = *(const float4*)rp;
      float4 r1 = *(const float4*)(rp + 4);
      __syncthreads();
      qws[lc + 0][lr] = qv.x + wb.x; qws[lc + 1][lr] = qv.y + wb.y;
      qws[lc + 2][lr] = qv.z + wb.z; qws[lc + 3][lr] = qv.w + wb.w;
      qrs[lc + 0][lr] = qv.x + rb.x; qrs[lc + 1][lr] = qv.y + rb.y;
      qrs[lc + 2][lr] = qv.z + rb.z; qrs[lc + 3][lr] = qv.w + rb.w;
      ks[lc + 0][lr] = kv.x; ks[lc + 1][lr] = kv.y;
      ks[lc + 2][lr] = kv.z; ks[lc + 3][lr] = kv.w;
      rs[lc2 + 0][lr2] = r0.x; rs[lc2 + 1][lr2] = r0.y;
      rs[lc2 + 2][lr2] = r0.z; rs[lc2 + 3][lr2] = r0.w;
      rs[lc2 + 4][lr2] = r1.x; rs[lc2 + 5][lr2] = r1.y;
      rs[lc2 + 6][lr2] = r1.z; rs[lc2 + 7][lr2] = r1.w;
      __syncthreads();
#pragma unroll
      for (int kk = 0; kk < 16; ++kk) {
        float aw[4], ar[4], bk[4];
#pragma unroll
        for (int i = 0; i < 4; ++i) { aw[i] = qws[kk][ty * 4 + i]; ar[i] = qrs[kk][ty * 4 + i]; }
#pragma unroll
        for (int j = 0; j < 4; ++j) bk[j] = ks[kk][tx * 4 + j];
#pragma unroll
        for (int i = 0; i < 4; ++i)
#pragma unroll
          for (int j = 0; j < 4; ++j)
            s[i][j] += aw[i] * bk[j] + ar[i] * rs[kk][(tx * 4 + j) - (ty * 4 + i) + 63];
      }
    }
    float fac[4], p[4][4];
#pragma unroll
    for (int i = 0; i < 4; ++i) {
      int gi = i0 + ty * 4 + i;
      float mx = -INFINITY;
#pragma unroll
      for (int j = 0; j < 4; ++j) {
        int gj = j0 + tx * 4 + j;
        s[i][j] = (gj > gi + MLEN) ? -INFINITY : s[i][j] * 0.125f;
        mx = fmaxf(mx, s[i][j]);
      }
#pragma unroll
      for (int o_ = 1; o_ < 16; o_ <<= 1) mx = fmaxf(mx, __shfl_xor(mx, o_, 64));
      float mnew = fmaxf(mrun[i], mx);
      fac[i] = expf(mrun[i] - mnew);
      float sum = 0.0f;
#pragma unroll
      for (int j = 0; j < 4; ++j) { p[i][j] = expf(s[i][j] - mnew); sum += p[i][j]; }
#pragma unroll
      for (int o_ = 1; o_ < 16; o_ <<= 1) sum += __shfl_xor(sum, o_, 64);
      lrun[i] = lrun[i] * fac[i] + sum;
      mrun[i] = mnew;
    }
    __syncthreads();
#pragma unroll
    for (int i = 0; i < 4; ++i)
#pragma unroll
      for (int j = 0; j < 4; ++j)
        ps[ty * 4 + i][tx * 4 + j] = p[i][j];
#pragma unroll
    for (int it = 0; it < 4; ++it) {
      int vr = (t >> 4) + it * 16, vc = (t & 15) * 4;
      float4 vv = *(const float4*)(wh + ((size_t)(j0 + vr) * B_ + b) * 3072 + 2048 + n * 64 + vc);
      vs[vr][vc + 0] = vv.x; vs[vr][vc + 1] = vv.y;
      vs[vr][vc + 2] = vv.z; vs[vr][vc + 3] = vv.w;
    }
    __syncthreads();
#pragma unroll
    for (int i = 0; i < 4; ++i)
#pragma unroll
      for (int d = 0; d < 4; ++d)
        o[i][d] *= fac[i];
    for (int kk = 0; kk < 64; ++kk) {
      float pv[4], vvv[4];
#pragma unroll
      for (int i = 0; i < 4; ++i) pv[i] = ps[ty * 4 + i][kk];
#pragma unroll
      for (int d = 0; d < 4; ++d) vvv[d] = vs[kk][tx * 4 + d];
#pragma unroll
      for (int i = 0; i < 4; ++i)
#pragma unroll
        for (int d = 0; d < 4; ++d)
          o[i][d] += pv[i] * vvv[d];
    }
  }
#pragma unroll
  for (int i = 0; i < 4; ++i) {
    float inv = 1.0f / lrun[i];
    f16x4 ov;
#pragma unroll
    for (int d = 0; d < 4; ++d) ov[d] = (_Float16)(o[i][d] * inv);
    *(f16x4*)(av + ((size_t)(i0 + ty * 4 + i) * B_ + b) * DM + n * 64 + tx * 4) = ov;
  }
}

// ---------------- host ----------------
extern "C" void kernel_launch(void* const* d_in, const int* in_sizes, int n_in,
                              void* d_out, int out_size, void* d_ws, size_t ws_size,
                              hipStream_t stream) {
  const float* inputs = (const float*)d_in[0];
  const float* mems   = (const float*)d_in[1];
  const float* rwb    = (const float*)d_in[2];
  const float* rrb    = (const float*)d_in[3];
  const float* qkv_w  = (const float*)d_in[4];
  const float* r_w    = (const float*)d_in[5];
  const float* o_w    = (const float*)d_in[6];
  const float* ln1_g  = (const float*)d_in[7];
  const float* ln1_b  = (const float*)d_in[8];
  const float* ff_w1  = (const float*)d_in[9];
  const float* ff_b1  = (const float*)d_in[10];
  const float* ff_w2  = (const float*)d_in[11];
  const float* ff_b2  = (const float*)d_in[12];
  const float* ln2_g  = (const float*)d_in[13];
  const float* ln2_b  = (const float*)d_in[14];
  const float* fin_g  = (const float*)d_in[15];
  const float* fin_b  = (const float*)d_in[16];
  float* out = (float*)d_out;

  float* ws = (float*)d_ws;
  float* xbuf = ws;                         // 2,097,152 f32
  float* wh   = xbuf + 2097152;             // 7,864,320 f32
  float* rk   = wh + 7864320;               //   655,360 f32
  _Float16* pe_h  = (_Float16*)(rk + 655360);   //   655,360 f16
  _Float16* h_h   = pe_h + 655360;              // 2,621,440 f16
  _Float16* av_h  = h_h + 2621440;              // 2,097,152 f16
  _Float16* ffh_h = av_h + 2097152;             // 8,388,608 f16
  _Float16* wb_h  = ffh_h + 8388608;            // 13,631,488 f16
  _Float16* wq = wb_h;
  _Float16* wr = wb_h + 3145728;
  _Float16* wo = wb_h + 4194304;
  _Float16* w1 = wb_h + 5242880;
  _Float16* w2 = wb_h + 9437184;

  pos_emb_kernel<<<KL, 256, 0, stream>>>(pe_h);

  const float* xcur = inputs;
  for (int l = 0; l < NL; ++l) {
    cast_w_kernel<<<13312, 256, 0, stream>>>(
        qkv_w + (size_t)l * 3145728, r_w + (size_t)l * 1048576,
        o_w + (size_t)l * 1048576, ff_w1 + (size_t)l * 4194304,
        ff_w2 + (size_t)l * 4194304, wb_h);
    // LN over [mems_l ; x] -> h_h (2560 rows, f16)
    ln_kernel<1><<<KL * B_, 256, 0, stream>>>(
        mems + (size_t)l * MLEN * B_ * DM, xcur,
        ln1_g + l * DM, ln1_b + l * DM, nullptr, h_h, MLEN * B_);
    // QKV projection -> wh fp32
    gemm_mfma<0, 0, 0, 0><<<dim3(3072 / 128, 2560 / 128), 256, 0, stream>>>(
        h_h, wq, nullptr, nullptr, wh, nullptr, 2560, 3072, DM);
    // r_head_k -> rk fp32
    gemm_mfma<0, 0, 0, 0><<<dim3(DM / 128, KL / 128), 256, 0, stream>>>(
        pe_h, wr, nullptr, nullptr, rk, nullptr, KL, DM, DM);
    // attention -> av_h f16
    attn_kernel<<<dim3(QLEN / 64, NH, B_), 256, 0, stream>>>(wh, rk, rwb, rrb, av_h);
    // out projection + residual -> xbuf fp32
    gemm_mfma<0, 0, 1, 0><<<dim3(DM / 128, (QLEN * B_) / 128), 256, 0, stream>>>(
        av_h, wo, nullptr, xcur, xbuf, nullptr, QLEN * B_, DM, DM);
    // FFN
    ln_kernel<1><<<QLEN * B_, 256, 0, stream>>>(
        xbuf, nullptr, ln2_g + l * DM, ln2_b + l * DM, nullptr, h_h, 1 << 30);
    gemm_mfma<1, 1, 0, 1><<<dim3(DFF / 128, (QLEN * B_) / 128), 256, 0, stream>>>(
        h_h, w1, ff_b1 + (size_t)l * DFF, nullptr, nullptr, ffh_h, QLEN * B_, DFF, DM);
    gemm_mfma<1, 0, 1, 0><<<dim3(DM / 128, (QLEN * B_) / 128), 256, 0, stream>>>(
        ffh_h, w2, ff_b2 + (size_t)l * DM, xbuf, xbuf, nullptr, QLEN * B_, DM, DFF);
    xcur = xbuf;
  }
  ln_kernel<0><<<QLEN * B_, 256, 0, stream>>>(xbuf, nullptr, fin_g, fin_b, out, nullptr, 1 << 30);
}

// Round 4
// 1613.515 us; speedup vs baseline: 5.6501x; 2.0062x over previous
//
#include <hip/hip_runtime.h>
#include <math.h>
#include <stdint.h>

#define DM    1024
#define NH    16
#define DH    64
#define NL    6
#define DFF   4096
#define QLEN  512
#define MLEN  128
#define B_    4
#define KL    640
#define CLAMP 512
#define EPS   1e-5f

typedef _Float16 f16x8 __attribute__((ext_vector_type(8)));
typedef _Float16 f16x4 __attribute__((ext_vector_type(4)));
typedef float    f32x4 __attribute__((ext_vector_type(4)));

// ---- async global->LDS, 16B per lane; LDS base must be wave-uniform ----
__device__ __forceinline__ void gload16(const void* g, void* l) {
  __builtin_amdgcn_global_load_lds(
      (const __attribute__((address_space(1))) void*)g,
      (__attribute__((address_space(3))) void*)l, 16, 0, 0);
}

// ---------------- block-wide sum over 256 threads (4 waves) ----------------
__device__ __forceinline__ float block_sum(float v, float* sm4) {
#pragma unroll
  for (int o = 32; o > 0; o >>= 1) v += __shfl_down(v, o, 64);
  int lane = threadIdx.x & 63, wid = threadIdx.x >> 6;
  if (lane == 0) sm4[wid] = v;
  __syncthreads();
  float r = sm4[0] + sm4[1] + sm4[2] + sm4[3];
  __syncthreads();
  return r;
}

// ---------------- sinusoidal relative position embedding (f16 out) ----------------
__global__ __launch_bounds__(256) void pos_emb_kernel(_Float16* __restrict__ pe) {
  int p = blockIdx.x;                       // 0..KL-1
  float pos = fminf((float)(KL - 1 - p), (float)CLAMP);
  for (int f = threadIdx.x; f < 512; f += 256) {
    float inv = powf(10000.0f, -(float)f * (1.0f / 512.0f));
    float a = pos * inv;
    pe[(size_t)p * DM + f]       = (_Float16)sinf(a);
    pe[(size_t)p * DM + 512 + f] = (_Float16)cosf(a);
  }
}

// ---------------- weight cast fp32 -> f16, one layer's 5 weights ----------------
__global__ __launch_bounds__(256) void cast_w_kernel(
    const float* __restrict__ s0, const float* __restrict__ s1,
    const float* __restrict__ s2, const float* __restrict__ s3,
    const float* __restrict__ s4, _Float16* __restrict__ dst) {
  size_t i = ((size_t)blockIdx.x * 256 + threadIdx.x) * 4;
  const float* src; size_t off;
  if (i < 3145728)      { src = s0; off = 0; }
  else if (i < 4194304) { src = s1; off = 3145728; }
  else if (i < 5242880) { src = s2; off = 4194304; }
  else if (i < 9437184) { src = s3; off = 5242880; }
  else                  { src = s4; off = 9437184; }
  float4 v = *(const float4*)(src + (i - off));
  f16x4 o = { (_Float16)v.x, (_Float16)v.y, (_Float16)v.z, (_Float16)v.w };
  *(f16x4*)(dst + i) = o;
}

// ---------------- LayerNorm over D=1024; optional 2-source concat ----------------
template <int OUTF16>
__global__ __launch_bounds__(256) void ln_kernel(
    const float* __restrict__ src0, const float* __restrict__ src1,
    const float* __restrict__ g, const float* __restrict__ b,
    float* __restrict__ outf, _Float16* __restrict__ outh, int rows0) {
  __shared__ float sm4[4];
  int row = blockIdx.x;
  const float* src = (row < rows0) ? (src0 + (size_t)row * DM)
                                   : (src1 + (size_t)(row - rows0) * DM);
  float4 v = ((const float4*)src)[threadIdx.x];
  float mean = block_sum(v.x + v.y + v.z + v.w, sm4) * (1.0f / DM);
  float dx = v.x - mean, dy = v.y - mean, dz = v.z - mean, dw = v.w - mean;
  float var = block_sum(dx * dx + dy * dy + dz * dz + dw * dw, sm4) * (1.0f / DM);
  float rstd = rsqrtf(var + EPS);
  float4 gg = ((const float4*)g)[threadIdx.x];
  float4 bb = ((const float4*)b)[threadIdx.x];
  float ox = dx * rstd * gg.x + bb.x;
  float oy = dy * rstd * gg.y + bb.y;
  float oz = dz * rstd * gg.z + bb.z;
  float ow = dw * rstd * gg.w + bb.w;
  if (OUTF16) {
    f16x4 o = { (_Float16)ox, (_Float16)oy, (_Float16)oz, (_Float16)ow };
    *(f16x4*)(outh + (size_t)row * DM + threadIdx.x * 4) = o;
  } else {
    float4 o = { ox, oy, oz, ow };
    ((float4*)(outf + (size_t)row * DM))[threadIdx.x] = o;
  }
}

// ---------------- f16 MFMA GEMM: C[m,n] = sum_k A[m,k]*B[n,k] ----------------
template <int BIAS, int RELU, int RESID, int OUTF16>
__global__ __launch_bounds__(256) void gemm_mfma(
    const _Float16* __restrict__ A, const _Float16* __restrict__ B,
    const float* __restrict__ bias, const float* __restrict__ resid,
    float* __restrict__ Cf, _Float16* __restrict__ Ch,
    int M, int N, int K) {
  __shared__ alignas(16) _Float16 As[128 * 32];
  __shared__ alignas(16) _Float16 Bs[128 * 32];
  const int t = threadIdx.x;
  const int lane = t & 63, wid = t >> 6;
  const int m0 = blockIdx.y * 128, n0 = blockIdx.x * 128;
  const int wm = (wid >> 1) * 64, wn = (wid & 1) * 64;

  const int c0 = wid * 64 + lane, c1 = c0 + 256;
  const _Float16* Ap0 = A + (size_t)(m0 + (c0 >> 2)) * K + (c0 & 3) * 8;
  const _Float16* Ap1 = A + (size_t)(m0 + (c1 >> 2)) * K + (c1 & 3) * 8;
  const _Float16* Bp0 = B + (size_t)(n0 + (c0 >> 2)) * K + (c0 & 3) * 8;
  const _Float16* Bp1 = B + (size_t)(n0 + (c1 >> 2)) * K + (c1 & 3) * 8;
  _Float16* Asw0 = &As[wid * 512];
  _Float16* Asw1 = &As[wid * 512 + 2048];
  _Float16* Bsw0 = &Bs[wid * 512];
  _Float16* Bsw1 = &Bs[wid * 512 + 2048];

  f32x4 acc[4][4] = {};
  for (int k0 = 0; k0 < K; k0 += 32) {
    __syncthreads();
    gload16(Ap0 + k0, Asw0);
    gload16(Ap1 + k0, Asw1);
    gload16(Bp0 + k0, Bsw0);
    gload16(Bp1 + k0, Bsw1);
    __syncthreads();
    f16x8 af[4], bf[4];
#pragma unroll
    for (int f = 0; f < 4; ++f) {
      af[f] = *(const f16x8*)&As[(wm + f * 16 + (lane & 15)) * 32 + (lane >> 4) * 8];
      bf[f] = *(const f16x8*)&Bs[(wn + f * 16 + (lane & 15)) * 32 + (lane >> 4) * 8];
    }
#pragma unroll
    for (int i = 0; i < 4; ++i)
#pragma unroll
      for (int j = 0; j < 4; ++j)
        acc[i][j] = __builtin_amdgcn_mfma_f32_16x16x32_f16(af[i], bf[j], acc[i][j], 0, 0, 0);
  }
#pragma unroll
  for (int i = 0; i < 4; ++i) {
#pragma unroll
    for (int j = 0; j < 4; ++j) {
      const int n = n0 + wn + j * 16 + (lane & 15);
      float bv = 0.0f;
      if (BIAS) bv = bias[n];
#pragma unroll
      for (int r = 0; r < 4; ++r) {
        const int m = m0 + wm + i * 16 + (lane >> 4) * 4 + r;
        float v = acc[i][j][r] + bv;
        if (RELU) v = fmaxf(v, 0.0f);
        if (RESID) v += resid[(size_t)m * N + n];
        if (OUTF16) Ch[(size_t)m * N + n] = (_Float16)v;
        else        Cf[(size_t)m * N + n] = v;
      }
    }
  }
}

// ---------------- MFMA flash-style relative attention ----------------
// grid (8 q-tiles, 16 heads, 4 batch); 256 threads = 4 waves, wave owns 16 q-rows.
// Per 64-key tile: AC = (Q+rwb)K^T (MFMA), QR = (Q+rrb)R^T (64x128 MFMA),
// S[i,j] = (AC[i,j] + QR[i, j-i+63])*scale, mask j>i+128, online softmax, O += P V (MFMA).
__global__ __launch_bounds__(256) void attn_kernel(
    const _Float16* __restrict__ wh,  // (KL*B_, 3072) f16 qkv projections
    const _Float16* __restrict__ rk,  // (KL, 1024) f16 r_head_k
    const float* __restrict__ rwb,    // (16,64)
    const float* __restrict__ rrb,    // (16,64)
    _Float16* __restrict__ av) {      // (QLEN, B_, 1024) f16
  __shared__ alignas(16) char smem[62976];
  _Float16* QW = (_Float16*)smem;      // [64][72] Q+rwb
  _Float16* QQ = QW + 64 * 72;         // [64][72] Q+rrb
  _Float16* RR = QQ + 64 * 72;         // [128][72] R tile
  _Float16* KS = RR + 128 * 72;        // [64][72] K tile, union V^T tile [d][j]
  _Float16* QRF = KS + 64 * 72;        // [64][132] QR out, union PS [64][72]
  _Float16* PS = QRF;

  const int i0 = blockIdx.x * 64, n = blockIdx.y, b = blockIdx.z;
  const int t = threadIdx.x, lane = t & 63, wid = t >> 6;
  const int g = lane >> 4, li = lane & 15;
  const int strip = wid * 16;

  // ---- stage Q strips with both biases (once per block) ----
  {
    int row = t >> 2, c = (t & 3) * 16;
    const _Float16* qp = wh + ((size_t)(MLEN + i0 + row) * B_ + b) * 3072 + n * 64 + c;
    f16x8 q0 = *(const f16x8*)qp, q1 = *(const f16x8*)(qp + 8);
    f16x8 a0, a1, b0, b1;
#pragma unroll
    for (int e = 0; e < 8; ++e) {
      float f0 = (float)q0[e], f1 = (float)q1[e];
      a0[e] = (_Float16)(f0 + rwb[n * 64 + c + e]);
      a1[e] = (_Float16)(f1 + rwb[n * 64 + c + 8 + e]);
      b0[e] = (_Float16)(f0 + rrb[n * 64 + c + e]);
      b1[e] = (_Float16)(f1 + rrb[n * 64 + c + 8 + e]);
    }
    *(f16x8*)&QW[row * 72 + c] = a0;
    *(f16x8*)&QW[row * 72 + c + 8] = a1;
    *(f16x8*)&QQ[row * 72 + c] = b0;
    *(f16x8*)&QQ[row * 72 + c + 8] = b1;
  }

  f32x4 o_[4] = {};
  float mrun[4], lrun[4];
#pragma unroll
  for (int r = 0; r < 4; ++r) { mrun[r] = -INFINITY; lrun[r] = 0.0f; }

  const int jend = i0 + 192;  // == min(i0+192, KL) since i0 <= 448
  for (int j0 = 0; j0 < jend; j0 += 64) {
    __syncthreads();  // Q staged; prev-tile PV reads of KS/PS done
    // ---- stage K tile ----
    {
      int row = t >> 2, c = (t & 3) * 16;
      const _Float16* kp = wh + ((size_t)(j0 + row) * B_ + b) * 3072 + 1024 + n * 64 + c;
      *(f16x8*)&KS[row * 72 + c] = *(const f16x8*)kp;
      *(f16x8*)&KS[row * 72 + c + 8] = *(const f16x8*)(kp + 8);
    }
    // ---- stage R tile (128 relative rows; clamped rows are masked anyway) ----
    {
      int row = t >> 1, c = (t & 1) * 32;
      int mrow = j0 - i0 + 448 + row;
      if (mrow > KL - 1) mrow = KL - 1;
      const _Float16* rp = rk + (size_t)mrow * DM + n * 64 + c;
#pragma unroll
      for (int cc = 0; cc < 32; cc += 8)
        *(f16x8*)&RR[row * 72 + c + cc] = *(const f16x8*)(rp + cc);
    }
    __syncthreads();
    // ---- MFMA: AC (4 col-frags) + QR (8 col-frags) over K=64 (2 ksteps) ----
    f32x4 acs[4] = {};
    f32x4 acq[8] = {};
#pragma unroll
    for (int ks_ = 0; ks_ < 2; ++ks_) {
      f16x8 aw = *(const f16x8*)&QW[(strip + li) * 72 + ks_ * 32 + g * 8];
      f16x8 ar = *(const f16x8*)&QQ[(strip + li) * 72 + ks_ * 32 + g * 8];
#pragma unroll
      for (int cf = 0; cf < 4; ++cf) {
        f16x8 bk = *(const f16x8*)&KS[(cf * 16 + li) * 72 + ks_ * 32 + g * 8];
        acs[cf] = __builtin_amdgcn_mfma_f32_16x16x32_f16(aw, bk, acs[cf], 0, 0, 0);
      }
#pragma unroll
      for (int cf = 0; cf < 8; ++cf) {
        f16x8 br = *(const f16x8*)&RR[(cf * 16 + li) * 72 + ks_ * 32 + g * 8];
        acq[cf] = __builtin_amdgcn_mfma_f32_16x16x32_f16(ar, br, acq[cf], 0, 0, 0);
      }
    }
    // ---- QR accumulators -> LDS (f16) for the rel-shift gather ----
#pragma unroll
    for (int cf = 0; cf < 8; ++cf)
#pragma unroll
      for (int r = 0; r < 4; ++r)
        QRF[(strip + g * 4 + r) * 132 + cf * 16 + li] = (_Float16)acq[cf][r];
    __syncthreads();
    // ---- online softmax (rows live in (g, r); cols across li and 4 frags) ----
    float pf[4][4], fac[4];
#pragma unroll
    for (int r = 0; r < 4; ++r) {
      int il = strip + g * 4 + r, gi = i0 + il;
      float sv[4], mx = -INFINITY;
#pragma unroll
      for (int cf = 0; cf < 4; ++cf) {
        int jl = cf * 16 + li;
        int m = jl - il + 63;  // in [0,127]
        float v = (acs[cf][r] + (float)QRF[il * 132 + m]) * 0.125f;
        if (j0 + jl > gi + MLEN) v = -INFINITY;
        sv[cf] = v;
        mx = fmaxf(mx, v);
      }
#pragma unroll
      for (int o2 = 1; o2 < 16; o2 <<= 1) mx = fmaxf(mx, __shfl_xor(mx, o2, 64));
      float mnew = fmaxf(mrun[r], mx);
      float fc = expf(mrun[r] - mnew);
      float sum = 0.0f;
#pragma unroll
      for (int cf = 0; cf < 4; ++cf) { pf[cf][r] = expf(sv[cf] - mnew); sum += pf[cf][r]; }
#pragma unroll
      for (int o2 = 1; o2 < 16; o2 <<= 1) sum += __shfl_xor(sum, o2, 64);
      lrun[r] = lrun[r] * fc + sum;
      mrun[r] = mnew;
      fac[r] = fc;
    }
    __syncthreads();  // all QRF gathers done before overwriting as PS
    // ---- P -> LDS (f16), stage V^T (union with KS) ----
#pragma unroll
    for (int cf = 0; cf < 4; ++cf)
#pragma unroll
      for (int r = 0; r < 4; ++r)
        PS[(strip + g * 4 + r) * 72 + cf * 16 + li] = (_Float16)pf[cf][r];
#pragma unroll
    for (int it = 0; it < 2; ++it) {
      int j = t & 63, d0 = (t >> 6) * 8 + it * 32;
      f16x8 vv = *(const f16x8*)(wh + ((size_t)(j0 + j) * B_ + b) * 3072 + 2048 + n * 64 + d0);
#pragma unroll
      for (int e = 0; e < 8; ++e) KS[(d0 + e) * 72 + j] = vv[e];
    }
    __syncthreads();
    // ---- PV: O = O*fac + P V ----
#pragma unroll
    for (int cf = 0; cf < 4; ++cf)
#pragma unroll
      for (int r = 0; r < 4; ++r)
        o_[cf][r] *= fac[r];
#pragma unroll
    for (int ks_ = 0; ks_ < 2; ++ks_) {
      f16x8 pa = *(const f16x8*)&PS[(strip + li) * 72 + ks_ * 32 + g * 8];
#pragma unroll
      for (int cf = 0; cf < 4; ++cf) {
        f16x8 bv = *(const f16x8*)&KS[(cf * 16 + li) * 72 + ks_ * 32 + g * 8];
        o_[cf] = __builtin_amdgcn_mfma_f32_16x16x32_f16(pa, bv, o_[cf], 0, 0, 0);
      }
    }
  }
  // ---- write O / lrun ----
#pragma unroll
  for (int cf = 0; cf < 4; ++cf)
#pragma unroll
    for (int r = 0; r < 4; ++r) {
      int row = strip + g * 4 + r;
      av[((size_t)(i0 + row) * B_ + b) * 1024 + n * 64 + cf * 16 + li] =
          (_Float16)(o_[cf][r] / lrun[r]);
    }
}

// ---------------- host ----------------
extern "C" void kernel_launch(void* const* d_in, const int* in_sizes, int n_in,
                              void* d_out, int out_size, void* d_ws, size_t ws_size,
                              hipStream_t stream) {
  const float* inputs = (const float*)d_in[0];
  const float* mems   = (const float*)d_in[1];
  const float* rwb    = (const float*)d_in[2];
  const float* rrb    = (const float*)d_in[3];
  const float* qkv_w  = (const float*)d_in[4];
  const float* r_w    = (const float*)d_in[5];
  const float* o_w    = (const float*)d_in[6];
  const float* ln1_g  = (const float*)d_in[7];
  const float* ln1_b  = (const float*)d_in[8];
  const float* ff_w1  = (const float*)d_in[9];
  const float* ff_b1  = (const float*)d_in[10];
  const float* ff_w2  = (const float*)d_in[11];
  const float* ff_b2  = (const float*)d_in[12];
  const float* ln2_g  = (const float*)d_in[13];
  const float* ln2_b  = (const float*)d_in[14];
  const float* fin_g  = (const float*)d_in[15];
  const float* fin_b  = (const float*)d_in[16];
  float* out = (float*)d_out;

  float* ws = (float*)d_ws;
  float* xbuf = ws;                               // 2,097,152 f32
  _Float16* fb = (_Float16*)(ws + 2097152);
  _Float16* wh_h  = fb;                           // 7,864,320
  _Float16* rk_h  = wh_h + 7864320;               //   655,360
  _Float16* pe_h  = rk_h + 655360;                //   655,360
  _Float16* h_h   = pe_h + 655360;                // 2,621,440
  _Float16* av_h  = h_h + 2621440;                // 2,097,152
  _Float16* ffh_h = av_h + 2097152;               // 8,388,608
  _Float16* wb_h  = ffh_h + 8388608;              // 13,631,488
  _Float16* wq = wb_h;
  _Float16* wr = wb_h + 3145728;
  _Float16* wo = wb_h + 4194304;
  _Float16* w1 = wb_h + 5242880;
  _Float16* w2 = wb_h + 9437184;

  pos_emb_kernel<<<KL, 256, 0, stream>>>(pe_h);

  const float* xcur = inputs;
  for (int l = 0; l < NL; ++l) {
    cast_w_kernel<<<13312, 256, 0, stream>>>(
        qkv_w + (size_t)l * 3145728, r_w + (size_t)l * 1048576,
        o_w + (size_t)l * 1048576, ff_w1 + (size_t)l * 4194304,
        ff_w2 + (size_t)l * 4194304, wb_h);
    // LN over [mems_l ; x] -> h_h (2560 rows, f16)
    ln_kernel<1><<<KL * B_, 256, 0, stream>>>(
        mems + (size_t)l * MLEN * B_ * DM, xcur,
        ln1_g + l * DM, ln1_b + l * DM, nullptr, h_h, MLEN * B_);
    // QKV projection -> wh f16
    gemm_mfma<0, 0, 0, 1><<<dim3(3072 / 128, 2560 / 128), 256, 0, stream>>>(
        h_h, wq, nullptr, nullptr, nullptr, wh_h, 2560, 3072, DM);
    // r_head_k -> rk f16
    gemm_mfma<0, 0, 0, 1><<<dim3(DM / 128, KL / 128), 256, 0, stream>>>(
        pe_h, wr, nullptr, nullptr, nullptr, rk_h, KL, DM, DM);
    // attention -> av_h f16
    attn_kernel<<<dim3(QLEN / 64, NH, B_), 256, 0, stream>>>(wh_h, rk_h, rwb, rrb, av_h);
    // out projection + residual -> xbuf fp32
    gemm_mfma<0, 0, 1, 0><<<dim3(DM / 128, (QLEN * B_) / 128), 256, 0, stream>>>(
        av_h, wo, nullptr, xcur, xbuf, nullptr, QLEN * B_, DM, DM);
    // FFN
    ln_kernel<1><<<QLEN * B_, 256, 0, stream>>>(
        xbuf, nullptr, ln2_g + l * DM, ln2_b + l * DM, nullptr, h_h, 1 << 30);
    gemm_mfma<1, 1, 0, 1><<<dim3(DFF / 128, (QLEN * B_) / 128), 256, 0, stream>>>(
        h_h, w1, ff_b1 + (size_t)l * DFF, nullptr, nullptr, ffh_h, QLEN * B_, DFF, DM);
    gemm_mfma<1, 0, 1, 0><<<dim3(DM / 128, (QLEN * B_) / 128), 256, 0, stream>>>(
        ffh_h, w2, ff_b2 + (size_t)l * DM, xbuf, xbuf, nullptr, QLEN * B_, DM, DFF);
    xcur = xbuf;
  }
  ln_kernel<0><<<QLEN * B_, 256, 0, stream>>>(xbuf, nullptr, fin_g, fin_b, out, nullptr, 1 << 30);
}

// Round 5
// 1235.377 us; speedup vs baseline: 7.3795x; 1.3061x over previous
//
#include <hip/hip_runtime.h>
#include <math.h>
#include <stdint.h>

#define DM    1024
#define NH    16
#define DH    64
#define NL    6
#define DFF   4096
#define QLEN  512
#define MLEN  128
#define B_    4
#define KL    640
#define CLAMP 512
#define EPS   1e-5f

typedef _Float16 f16x8 __attribute__((ext_vector_type(8)));
typedef _Float16 f16x4 __attribute__((ext_vector_type(4)));
typedef float    f32x4 __attribute__((ext_vector_type(4)));

// ---- async global->LDS, 16B per lane; LDS base must be wave-uniform ----
__device__ __forceinline__ void gload16(const void* g, void* l) {
  __builtin_amdgcn_global_load_lds(
      (const __attribute__((address_space(1))) void*)g,
      (__attribute__((address_space(3))) void*)l, 16, 0, 0);
}

// ---------------- block-wide sum over 256 threads (4 waves) ----------------
__device__ __forceinline__ float block_sum(float v, float* sm4) {
#pragma unroll
  for (int o = 32; o > 0; o >>= 1) v += __shfl_down(v, o, 64);
  int lane = threadIdx.x & 63, wid = threadIdx.x >> 6;
  if (lane == 0) sm4[wid] = v;
  __syncthreads();
  float r = sm4[0] + sm4[1] + sm4[2] + sm4[3];
  __syncthreads();
  return r;
}

// ---------------- sinusoidal relative position embedding (f16 out) ----------------
__global__ __launch_bounds__(256) void pos_emb_kernel(_Float16* __restrict__ pe) {
  int p = blockIdx.x;                       // 0..KL-1
  float pos = fminf((float)(KL - 1 - p), (float)CLAMP);
  for (int f = threadIdx.x; f < 512; f += 256) {
    float inv = powf(10000.0f, -(float)f * (1.0f / 512.0f));
    float a = pos * inv;
    pe[(size_t)p * DM + f]       = (_Float16)sinf(a);
    pe[(size_t)p * DM + 512 + f] = (_Float16)cosf(a);
  }
}

// ---------------- weight cast fp32 -> f16, one layer's 5 weights ----------------
__global__ __launch_bounds__(256) void cast_w_kernel(
    const float* __restrict__ s0, const float* __restrict__ s1,
    const float* __restrict__ s2, const float* __restrict__ s3,
    const float* __restrict__ s4, _Float16* __restrict__ dst) {
  size_t i = ((size_t)blockIdx.x * 256 + threadIdx.x) * 4;
  const float* src; size_t off;
  if (i < 3145728)      { src = s0; off = 0; }
  else if (i < 4194304) { src = s1; off = 3145728; }
  else if (i < 5242880) { src = s2; off = 4194304; }
  else if (i < 9437184) { src = s3; off = 5242880; }
  else                  { src = s4; off = 9437184; }
  float4 v = *(const float4*)(src + (i - off));
  f16x4 o = { (_Float16)v.x, (_Float16)v.y, (_Float16)v.z, (_Float16)v.w };
  *(f16x4*)(dst + i) = o;
}

// ---------------- LayerNorm over D=1024; optional 2-source concat ----------------
template <int OUTF16>
__global__ __launch_bounds__(256) void ln_kernel(
    const float* __restrict__ src0, const float* __restrict__ src1,
    const float* __restrict__ g, const float* __restrict__ b,
    float* __restrict__ outf, _Float16* __restrict__ outh, int rows0) {
  __shared__ float sm4[4];
  int row = blockIdx.x;
  const float* src = (row < rows0) ? (src0 + (size_t)row * DM)
                                   : (src1 + (size_t)(row - rows0) * DM);
  float4 v = ((const float4*)src)[threadIdx.x];
  float mean = block_sum(v.x + v.y + v.z + v.w, sm4) * (1.0f / DM);
  float dx = v.x - mean, dy = v.y - mean, dz = v.z - mean, dw = v.w - mean;
  float var = block_sum(dx * dx + dy * dy + dz * dz + dw * dw, sm4) * (1.0f / DM);
  float rstd = rsqrtf(var + EPS);
  float4 gg = ((const float4*)g)[threadIdx.x];
  float4 bb = ((const float4*)b)[threadIdx.x];
  float ox = dx * rstd * gg.x + bb.x;
  float oy = dy * rstd * gg.y + bb.y;
  float oz = dz * rstd * gg.z + bb.z;
  float ow = dw * rstd * gg.w + bb.w;
  if (OUTF16) {
    f16x4 o = { (_Float16)ox, (_Float16)oy, (_Float16)oz, (_Float16)ow };
    *(f16x4*)(outh + (size_t)row * DM + threadIdx.x * 4) = o;
  } else {
    float4 o = { ox, oy, oz, ow };
    ((float4*)(outf + (size_t)row * DM))[threadIdx.x] = o;
  }
}

// ---------------- f16 MFMA GEMM: C[m,n] = sum_k A[m,k]*B[n,k] ----------------
// 128x128 tile, BK=32, 256 threads (4 waves, 2x2 of 64x64), global_load_lds staging
template <int BIAS, int RELU, int RESID, int OUTF16>
__global__ __launch_bounds__(256) void gemm_mfma(
    const _Float16* __restrict__ A, const _Float16* __restrict__ B,
    const float* __restrict__ bias, const float* __restrict__ resid,
    float* __restrict__ Cf, _Float16* __restrict__ Ch,
    int M, int N, int K) {
  __shared__ alignas(16) _Float16 As[128 * 32];
  __shared__ alignas(16) _Float16 Bs[128 * 32];
  const int t = threadIdx.x;
  const int lane = t & 63, wid = t >> 6;
  const int m0 = blockIdx.y * 128, n0 = blockIdx.x * 128;
  const int wm = (wid >> 1) * 64, wn = (wid & 1) * 64;

  const int c0 = wid * 64 + lane, c1 = c0 + 256;
  const _Float16* Ap0 = A + (size_t)(m0 + (c0 >> 2)) * K + (c0 & 3) * 8;
  const _Float16* Ap1 = A + (size_t)(m0 + (c1 >> 2)) * K + (c1 & 3) * 8;
  const _Float16* Bp0 = B + (size_t)(n0 + (c0 >> 2)) * K + (c0 & 3) * 8;
  const _Float16* Bp1 = B + (size_t)(n0 + (c1 >> 2)) * K + (c1 & 3) * 8;
  _Float16* Asw0 = &As[wid * 512];
  _Float16* Asw1 = &As[wid * 512 + 2048];
  _Float16* Bsw0 = &Bs[wid * 512];
  _Float16* Bsw1 = &Bs[wid * 512 + 2048];

  f32x4 acc[4][4] = {};
  for (int k0 = 0; k0 < K; k0 += 32) {
    __syncthreads();
    gload16(Ap0 + k0, Asw0);
    gload16(Ap1 + k0, Asw1);
    gload16(Bp0 + k0, Bsw0);
    gload16(Bp1 + k0, Bsw1);
    __syncthreads();
    f16x8 af[4], bf[4];
#pragma unroll
    for (int f = 0; f < 4; ++f) {
      af[f] = *(const f16x8*)&As[(wm + f * 16 + (lane & 15)) * 32 + (lane >> 4) * 8];
      bf[f] = *(const f16x8*)&Bs[(wn + f * 16 + (lane & 15)) * 32 + (lane >> 4) * 8];
    }
#pragma unroll
    for (int i = 0; i < 4; ++i)
#pragma unroll
      for (int j = 0; j < 4; ++j)
        acc[i][j] = __builtin_amdgcn_mfma_f32_16x16x32_f16(af[i], bf[j], acc[i][j], 0, 0, 0);
  }
#pragma unroll
  for (int i = 0; i < 4; ++i) {
#pragma unroll
    for (int j = 0; j < 4; ++j) {
      const int n = n0 + wn + j * 16 + (lane & 15);
      float bv = 0.0f;
      if (BIAS) bv = bias[n];
#pragma unroll
      for (int r = 0; r < 4; ++r) {
        const int m = m0 + wm + i * 16 + (lane >> 4) * 4 + r;
        float v = acc[i][j][r] + bv;
        if (RELU) v = fmaxf(v, 0.0f);
        if (RESID) v += resid[(size_t)m * N + n];
        if (OUTF16) Ch[(size_t)m * N + n] = (_Float16)v;
        else        Cf[(size_t)m * N + n] = v;
      }
    }
  }
}

// ---------------- split-K GEMM: partial[z][m][n] = sum_{k in slice z} A[m,k]B[n,k] ----
// blockIdx.z = K-slice of length Ks; f16 partials
__global__ __launch_bounds__(256) void gemm_sk(
    const _Float16* __restrict__ A, const _Float16* __restrict__ B,
    _Float16* __restrict__ pk, int M, int N, int K, int Ks) {
  __shared__ alignas(16) _Float16 As[128 * 32];
  __shared__ alignas(16) _Float16 Bs[128 * 32];
  const int t = threadIdx.x;
  const int lane = t & 63, wid = t >> 6;
  const int m0 = blockIdx.y * 128, n0 = blockIdx.x * 128;
  const int z = blockIdx.z;
  const int kbase = z * Ks;
  const int wm = (wid >> 1) * 64, wn = (wid & 1) * 64;

  const int c0 = wid * 64 + lane, c1 = c0 + 256;
  const _Float16* Ap0 = A + (size_t)(m0 + (c0 >> 2)) * K + kbase + (c0 & 3) * 8;
  const _Float16* Ap1 = A + (size_t)(m0 + (c1 >> 2)) * K + kbase + (c1 & 3) * 8;
  const _Float16* Bp0 = B + (size_t)(n0 + (c0 >> 2)) * K + kbase + (c0 & 3) * 8;
  const _Float16* Bp1 = B + (size_t)(n0 + (c1 >> 2)) * K + kbase + (c1 & 3) * 8;
  _Float16* Asw0 = &As[wid * 512];
  _Float16* Asw1 = &As[wid * 512 + 2048];
  _Float16* Bsw0 = &Bs[wid * 512];
  _Float16* Bsw1 = &Bs[wid * 512 + 2048];

  f32x4 acc[4][4] = {};
  for (int k0 = 0; k0 < Ks; k0 += 32) {
    __syncthreads();
    gload16(Ap0 + k0, Asw0);
    gload16(Ap1 + k0, Asw1);
    gload16(Bp0 + k0, Bsw0);
    gload16(Bp1 + k0, Bsw1);
    __syncthreads();
    f16x8 af[4], bf[4];
#pragma unroll
    for (int f = 0; f < 4; ++f) {
      af[f] = *(const f16x8*)&As[(wm + f * 16 + (lane & 15)) * 32 + (lane >> 4) * 8];
      bf[f] = *(const f16x8*)&Bs[(wn + f * 16 + (lane & 15)) * 32 + (lane >> 4) * 8];
    }
#pragma unroll
    for (int i = 0; i < 4; ++i)
#pragma unroll
      for (int j = 0; j < 4; ++j)
        acc[i][j] = __builtin_amdgcn_mfma_f32_16x16x32_f16(af[i], bf[j], acc[i][j], 0, 0, 0);
  }
  _Float16* out = pk + (size_t)z * M * N;
#pragma unroll
  for (int i = 0; i < 4; ++i)
#pragma unroll
    for (int j = 0; j < 4; ++j) {
      const int n = n0 + wn + j * 16 + (lane & 15);
#pragma unroll
      for (int r = 0; r < 4; ++r) {
        const int m = m0 + wm + i * 16 + (lane >> 4) * 4 + r;
        out[(size_t)m * N + n] = (_Float16)acc[i][j][r];
      }
    }
}

// ---------------- split-K reduce: C = sum_z pk[z] (+bias)(relu)(+resid) ----------------
// 256 threads x 8 elems; N must be power of 2 (Nmask = N-1)
template <int SK, int BIAS, int RELU, int RESID, int OUTF16>
__global__ __launch_bounds__(256) void reduce_k(
    const _Float16* __restrict__ pk, const float* __restrict__ bias,
    const float* __restrict__ resid, float* __restrict__ Cf,
    _Float16* __restrict__ Ch, int MN, int Nmask) {
  const int idx = (blockIdx.x * 256 + threadIdx.x) * 8;
  float s[8] = {};
#pragma unroll
  for (int zz = 0; zz < SK; ++zz) {
    f16x8 v = *(const f16x8*)(pk + (size_t)zz * MN + idx);
#pragma unroll
    for (int e = 0; e < 8; ++e) s[e] += (float)v[e];
  }
  if (BIAS) {
    const int n0 = idx & Nmask;
#pragma unroll
    for (int e = 0; e < 8; ++e) s[e] += bias[n0 + e];
  }
  if (RELU)
#pragma unroll
    for (int e = 0; e < 8; ++e) s[e] = fmaxf(s[e], 0.0f);
  if (RESID) {
    float4 r0 = *(const float4*)(resid + idx);
    float4 r1 = *(const float4*)(resid + idx + 4);
    s[0] += r0.x; s[1] += r0.y; s[2] += r0.z; s[3] += r0.w;
    s[4] += r1.x; s[5] += r1.y; s[6] += r1.z; s[7] += r1.w;
  }
  if (OUTF16) {
    f16x8 o;
#pragma unroll
    for (int e = 0; e < 8; ++e) o[e] = (_Float16)s[e];
    *(f16x8*)(Ch + idx) = o;
  } else {
    float4 o0 = { s[0], s[1], s[2], s[3] };
    float4 o1 = { s[4], s[5], s[6], s[7] };
    *(float4*)(Cf + idx) = o0;
    *(float4*)(Cf + idx + 4) = o1;
  }
}

// ---------------- MFMA flash-style relative attention ----------------
__global__ __launch_bounds__(256) void attn_kernel(
    const _Float16* __restrict__ wh,  // (KL*B_, 3072) f16 qkv projections
    const _Float16* __restrict__ rk,  // (KL, 1024) f16 r_head_k
    const float* __restrict__ rwb,    // (16,64)
    const float* __restrict__ rrb,    // (16,64)
    _Float16* __restrict__ av) {      // (QLEN, B_, 1024) f16
  __shared__ alignas(16) char smem[62976];
  _Float16* QW = (_Float16*)smem;      // [64][72] Q+rwb
  _Float16* QQ = QW + 64 * 72;         // [64][72] Q+rrb
  _Float16* RR = QQ + 64 * 72;         // [128][72] R tile
  _Float16* KS = RR + 128 * 72;        // [64][72] K tile, union V^T tile [d][j]
  _Float16* QRF = KS + 64 * 72;        // [64][132] QR out, union PS [64][72]
  _Float16* PS = QRF;

  const int i0 = blockIdx.x * 64, n = blockIdx.y, b = blockIdx.z;
  const int t = threadIdx.x, lane = t & 63, wid = t >> 6;
  const int g = lane >> 4, li = lane & 15;
  const int strip = wid * 16;

  {
    int row = t >> 2, c = (t & 3) * 16;
    const _Float16* qp = wh + ((size_t)(MLEN + i0 + row) * B_ + b) * 3072 + n * 64 + c;
    f16x8 q0 = *(const f16x8*)qp, q1 = *(const f16x8*)(qp + 8);
    f16x8 a0, a1, b0, b1;
#pragma unroll
    for (int e = 0; e < 8; ++e) {
      float f0 = (float)q0[e], f1 = (float)q1[e];
      a0[e] = (_Float16)(f0 + rwb[n * 64 + c + e]);
      a1[e] = (_Float16)(f1 + rwb[n * 64 + c + 8 + e]);
      b0[e] = (_Float16)(f0 + rrb[n * 64 + c + e]);
      b1[e] = (_Float16)(f1 + rrb[n * 64 + c + 8 + e]);
    }
    *(f16x8*)&QW[row * 72 + c] = a0;
    *(f16x8*)&QW[row * 72 + c + 8] = a1;
    *(f16x8*)&QQ[row * 72 + c] = b0;
    *(f16x8*)&QQ[row * 72 + c + 8] = b1;
  }

  f32x4 o_[4] = {};
  float mrun[4], lrun[4];
#pragma unroll
  for (int r = 0; r < 4; ++r) { mrun[r] = -INFINITY; lrun[r] = 0.0f; }

  const int jend = i0 + 192;
  for (int j0 = 0; j0 < jend; j0 += 64) {
    __syncthreads();
    {
      int row = t >> 2, c = (t & 3) * 16;
      const _Float16* kp = wh + ((size_t)(j0 + row) * B_ + b) * 3072 + 1024 + n * 64 + c;
      *(f16x8*)&KS[row * 72 + c] = *(const f16x8*)kp;
      *(f16x8*)&KS[row * 72 + c + 8] = *(const f16x8*)(kp + 8);
    }
    {
      int row = t >> 1, c = (t & 1) * 32;
      int mrow = j0 - i0 + 448 + row;
      if (mrow > KL - 1) mrow = KL - 1;
      const _Float16* rp = rk + (size_t)mrow * DM + n * 64 + c;
#pragma unroll
      for (int cc = 0; cc < 32; cc += 8)
        *(f16x8*)&RR[row * 72 + c + cc] = *(const f16x8*)(rp + cc);
    }
    __syncthreads();
    f32x4 acs[4] = {};
    f32x4 acq[8] = {};
#pragma unroll
    for (int ks_ = 0; ks_ < 2; ++ks_) {
      f16x8 aw = *(const f16x8*)&QW[(strip + li) * 72 + ks_ * 32 + g * 8];
      f16x8 ar = *(const f16x8*)&QQ[(strip + li) * 72 + ks_ * 32 + g * 8];
#pragma unroll
      for (int cf = 0; cf < 4; ++cf) {
        f16x8 bk = *(const f16x8*)&KS[(cf * 16 + li) * 72 + ks_ * 32 + g * 8];
        acs[cf] = __builtin_amdgcn_mfma_f32_16x16x32_f16(aw, bk, acs[cf], 0, 0, 0);
      }
#pragma unroll
      for (int cf = 0; cf < 8; ++cf) {
        f16x8 br = *(const f16x8*)&RR[(cf * 16 + li) * 72 + ks_ * 32 + g * 8];
        acq[cf] = __builtin_amdgcn_mfma_f32_16x16x32_f16(ar, br, acq[cf], 0, 0, 0);
      }
    }
#pragma unroll
    for (int cf = 0; cf < 8; ++cf)
#pragma unroll
      for (int r = 0; r < 4; ++r)
        QRF[(strip + g * 4 + r) * 132 + cf * 16 + li] = (_Float16)acq[cf][r];
    __syncthreads();
    float pf[4][4], fac[4];
#pragma unroll
    for (int r = 0; r < 4; ++r) {
      int il = strip + g * 4 + r, gi = i0 + il;
      float sv[4], mx = -INFINITY;
#pragma unroll
      for (int cf = 0; cf < 4; ++cf) {
        int jl = cf * 16 + li;
        int m = jl - il + 63;
        float v = (acs[cf][r] + (float)QRF[il * 132 + m]) * 0.125f;
        if (j0 + jl > gi + MLEN) v = -INFINITY;
        sv[cf] = v;
        mx = fmaxf(mx, v);
      }
#pragma unroll
      for (int o2 = 1; o2 < 16; o2 <<= 1) mx = fmaxf(mx, __shfl_xor(mx, o2, 64));
      float mnew = fmaxf(mrun[r], mx);
      float fc = expf(mrun[r] - mnew);
      float sum = 0.0f;
#pragma unroll
      for (int cf = 0; cf < 4; ++cf) { pf[cf][r] = expf(sv[cf] - mnew); sum += pf[cf][r]; }
#pragma unroll
      for (int o2 = 1; o2 < 16; o2 <<= 1) sum += __shfl_xor(sum, o2, 64);
      lrun[r] = lrun[r] * fc + sum;
      mrun[r] = mnew;
      fac[r] = fc;
    }
    __syncthreads();
#pragma unroll
    for (int cf = 0; cf < 4; ++cf)
#pragma unroll
      for (int r = 0; r < 4; ++r)
        PS[(strip + g * 4 + r) * 72 + cf * 16 + li] = (_Float16)pf[cf][r];
#pragma unroll
    for (int it = 0; it < 2; ++it) {
      int j = t & 63, d0 = (t >> 6) * 8 + it * 32;
      f16x8 vv = *(const f16x8*)(wh + ((size_t)(j0 + j) * B_ + b) * 3072 + 2048 + n * 64 + d0);
#pragma unroll
      for (int e = 0; e < 8; ++e) KS[(d0 + e) * 72 + j] = vv[e];
    }
    __syncthreads();
#pragma unroll
    for (int cf = 0; cf < 4; ++cf)
#pragma unroll
      for (int r = 0; r < 4; ++r)
        o_[cf][r] *= fac[r];
#pragma unroll
    for (int ks_ = 0; ks_ < 2; ++ks_) {
      f16x8 pa = *(const f16x8*)&PS[(strip + li) * 72 + ks_ * 32 + g * 8];
#pragma unroll
      for (int cf = 0; cf < 4; ++cf) {
        f16x8 bv = *(const f16x8*)&KS[(cf * 16 + li) * 72 + ks_ * 32 + g * 8];
        o_[cf] = __builtin_amdgcn_mfma_f32_16x16x32_f16(pa, bv, o_[cf], 0, 0, 0);
      }
    }
  }
#pragma unroll
  for (int cf = 0; cf < 4; ++cf)
#pragma unroll
    for (int r = 0; r < 4; ++r) {
      int row = strip + g * 4 + r;
      av[((size_t)(i0 + row) * B_ + b) * 1024 + n * 64 + cf * 16 + li] =
          (_Float16)(o_[cf][r] / lrun[r]);
    }
}

// ---------------- host ----------------
extern "C" void kernel_launch(void* const* d_in, const int* in_sizes, int n_in,
                              void* d_out, int out_size, void* d_ws, size_t ws_size,
                              hipStream_t stream) {
  const float* inputs = (const float*)d_in[0];
  const float* mems   = (const float*)d_in[1];
  const float* rwb    = (const float*)d_in[2];
  const float* rrb    = (const float*)d_in[3];
  const float* qkv_w  = (const float*)d_in[4];
  const float* r_w    = (const float*)d_in[5];
  const float* o_w    = (const float*)d_in[6];
  const float* ln1_g  = (const float*)d_in[7];
  const float* ln1_b  = (const float*)d_in[8];
  const float* ff_w1  = (const float*)d_in[9];
  const float* ff_b1  = (const float*)d_in[10];
  const float* ff_w2  = (const float*)d_in[11];
  const float* ff_b2  = (const float*)d_in[12];
  const float* ln2_g  = (const float*)d_in[13];
  const float* ln2_b  = (const float*)d_in[14];
  const float* fin_g  = (const float*)d_in[15];
  const float* fin_b  = (const float*)d_in[16];
  float* out = (float*)d_out;

  float* ws = (float*)d_ws;
  float* xbuf = ws;                               // 2,097,152 f32
  _Float16* fb = (_Float16*)(ws + 2097152);
  _Float16* wh_h  = fb;                           // 7,864,320
  _Float16* rk_h  = wh_h + 7864320;               //   655,360
  _Float16* pe_h  = rk_h + 655360;                //   655,360
  _Float16* h_h   = pe_h + 655360;                // 2,621,440
  _Float16* av_h  = h_h + 2621440;                // 2,097,152
  _Float16* ffh_h = av_h + 2097152;               // 8,388,608
  _Float16* wb_h  = ffh_h + 8388608;              // 13,631,488
  _Float16* wq = wb_h;
  _Float16* wr = wb_h + 3145728;
  _Float16* wo = wb_h + 4194304;
  _Float16* w1 = wb_h + 5242880;
  _Float16* w2 = wb_h + 9437184;
  // split-K partial overlays (regions dead at time of use):
  _Float16* pk_big = wh_h;   // 8,388,608 f16 needed; wh_h+rk_h = 8,519,680 (dead after attn)
  _Float16* pk_rk  = ffh_h;  // 5,242,880 f16 needed; ffh dead before FF1

  pos_emb_kernel<<<KL, 256, 0, stream>>>(pe_h);

  const float* xcur = inputs;
  for (int l = 0; l < NL; ++l) {
    cast_w_kernel<<<13312, 256, 0, stream>>>(
        qkv_w + (size_t)l * 3145728, r_w + (size_t)l * 1048576,
        o_w + (size_t)l * 1048576, ff_w1 + (size_t)l * 4194304,
        ff_w2 + (size_t)l * 4194304, wb_h);
    // LN over [mems_l ; x] -> h_h (2560 rows, f16)
    ln_kernel<1><<<KL * B_, 256, 0, stream>>>(
        mems + (size_t)l * MLEN * B_ * DM, xcur,
        ln1_g + l * DM, ln1_b + l * DM, nullptr, h_h, MLEN * B_);
    // QKV projection -> wh f16 (480 blocks, leave fused)
    gemm_mfma<0, 0, 0, 1><<<dim3(3072 / 128, 2560 / 128), 256, 0, stream>>>(
        h_h, wq, nullptr, nullptr, nullptr, wh_h, 2560, 3072, DM);
    // r_head_k: split-K=8 (320 blocks) -> reduce -> rk f16
    gemm_sk<<<dim3(DM / 128, KL / 128, 8), 256, 0, stream>>>(
        pe_h, wr, pk_rk, KL, DM, DM, DM / 8);
    reduce_k<8, 0, 0, 0, 1><<<KL * DM / 2048, 256, 0, stream>>>(
        pk_rk, nullptr, nullptr, nullptr, rk_h, KL * DM, DM - 1);
    // attention -> av_h f16
    attn_kernel<<<dim3(QLEN / 64, NH, B_), 256, 0, stream>>>(wh_h, rk_h, rwb, rrb, av_h);
    // out projection: split-K=4 (512 blocks) -> reduce(+resid) -> xbuf fp32
    gemm_sk<<<dim3(DM / 128, (QLEN * B_) / 128, 4), 256, 0, stream>>>(
        av_h, wo, pk_big, QLEN * B_, DM, DM, DM / 4);
    reduce_k<4, 0, 0, 1, 0><<<QLEN * B_ * DM / 2048, 256, 0, stream>>>(
        pk_big, nullptr, xcur, xbuf, nullptr, QLEN * B_ * DM, DM - 1);
    // FFN
    ln_kernel<1><<<QLEN * B_, 256, 0, stream>>>(
        xbuf, nullptr, ln2_g + l * DM, ln2_b + l * DM, nullptr, h_h, 1 << 30);
    gemm_mfma<1, 1, 0, 1><<<dim3(DFF / 128, (QLEN * B_) / 128), 256, 0, stream>>>(
        h_h, w1, ff_b1 + (size_t)l * DFF, nullptr, nullptr, ffh_h, QLEN * B_, DFF, DM);
    // FF2: split-K=4 (512 blocks, Ks=1024) -> reduce(+bias+resid) -> xbuf fp32
    gemm_sk<<<dim3(DM / 128, (QLEN * B_) / 128, 4), 256, 0, stream>>>(
        ffh_h, w2, pk_big, QLEN * B_, DM, DFF, DFF / 4);
    reduce_k<4, 1, 0, 1, 0><<<QLEN * B_ * DM / 2048, 256, 0, stream>>>(
        pk_big, ff_b2 + (size_t)l * DM, xbuf, xbuf, nullptr, QLEN * B_ * DM, DM - 1);
    xcur = xbuf;
  }
  ln_kernel<0><<<QLEN * B_, 256, 0, stream>>>(xbuf, nullptr, fin_g, fin_b, out, nullptr, 1 << 30);
}

// Round 7
// 1226.800 us; speedup vs baseline: 7.4311x; 1.0070x over previous
//
#include <hip/hip_runtime.h>
#include <math.h>
#include <stdint.h>

#define DM    1024
#define NH    16
#define DH    64
#define NL    6
#define DFF   4096
#define QLEN  512
#define MLEN  128
#define B_    4
#define KL    640
#define CLAMP 512
#define EPS   1e-5f

typedef _Float16 f16x8 __attribute__((ext_vector_type(8)));
typedef _Float16 f16x4 __attribute__((ext_vector_type(4)));
typedef float    f32x4 __attribute__((ext_vector_type(4)));

// ---- async global->LDS, 16B per lane; LDS base must be wave-uniform ----
__device__ __forceinline__ void gload16(const void* g, void* l) {
  __builtin_amdgcn_global_load_lds(
      (const __attribute__((address_space(1))) void*)g,
      (__attribute__((address_space(3))) void*)l, 16, 0, 0);
}

// ---------------- block-wide sum over 256 threads (4 waves) ----------------
__device__ __forceinline__ float block_sum(float v, float* sm4) {
#pragma unroll
  for (int o = 32; o > 0; o >>= 1) v += __shfl_down(v, o, 64);
  int lane = threadIdx.x & 63, wid = threadIdx.x >> 6;
  if (lane == 0) sm4[wid] = v;
  __syncthreads();
  float r = sm4[0] + sm4[1] + sm4[2] + sm4[3];
  __syncthreads();
  return r;
}

// ---------------- sinusoidal relative position embedding (f16 out) ----------------
__global__ __launch_bounds__(256) void pos_emb_kernel(_Float16* __restrict__ pe) {
  int p = blockIdx.x;                       // 0..KL-1
  float pos = fminf((float)(KL - 1 - p), (float)CLAMP);
  for (int f = threadIdx.x; f < 512; f += 256) {
    float inv = powf(10000.0f, -(float)f * (1.0f / 512.0f));
    float a = pos * inv;
    pe[(size_t)p * DM + f]       = (_Float16)sinf(a);
    pe[(size_t)p * DM + 512 + f] = (_Float16)cosf(a);
  }
}

// ---------------- weight cast fp32 -> f16, one layer's 5 weights ----------------
__global__ __launch_bounds__(256) void cast_w_kernel(
    const float* __restrict__ s0, const float* __restrict__ s1,
    const float* __restrict__ s2, const float* __restrict__ s3,
    const float* __restrict__ s4, _Float16* __restrict__ dst) {
  size_t i = ((size_t)blockIdx.x * 256 + threadIdx.x) * 4;
  const float* src; size_t off;
  if (i < 3145728)      { src = s0; off = 0; }
  else if (i < 4194304) { src = s1; off = 3145728; }
  else if (i < 5242880) { src = s2; off = 4194304; }
  else if (i < 9437184) { src = s3; off = 5242880; }
  else                  { src = s4; off = 9437184; }
  float4 v = *(const float4*)(src + (i - off));
  f16x4 o = { (_Float16)v.x, (_Float16)v.y, (_Float16)v.z, (_Float16)v.w };
  *(f16x4*)(dst + i) = o;
}

// ---------------- LayerNorm over D=1024; optional 2-source concat ----------------
template <int OUTF16>
__global__ __launch_bounds__(256) void ln_kernel(
    const float* __restrict__ src0, const float* __restrict__ src1,
    const float* __restrict__ g, const float* __restrict__ b,
    float* __restrict__ outf, _Float16* __restrict__ outh, int rows0) {
  __shared__ float sm4[4];
  int row = blockIdx.x;
  const float* src = (row < rows0) ? (src0 + (size_t)row * DM)
                                   : (src1 + (size_t)(row - rows0) * DM);
  float4 v = ((const float4*)src)[threadIdx.x];
  float mean = block_sum(v.x + v.y + v.z + v.w, sm4) * (1.0f / DM);
  float dx = v.x - mean, dy = v.y - mean, dz = v.z - mean, dw = v.w - mean;
  float var = block_sum(dx * dx + dy * dy + dz * dz + dw * dw, sm4) * (1.0f / DM);
  float rstd = rsqrtf(var + EPS);
  float4 gg = ((const float4*)g)[threadIdx.x];
  float4 bb = ((const float4*)b)[threadIdx.x];
  float ox = dx * rstd * gg.x + bb.x;
  float oy = dy * rstd * gg.y + bb.y;
  float oz = dz * rstd * gg.z + bb.z;
  float ow = dw * rstd * gg.w + bb.w;
  if (OUTF16) {
    f16x4 o = { (_Float16)ox, (_Float16)oy, (_Float16)oz, (_Float16)ow };
    *(f16x4*)(outh + (size_t)row * DM + threadIdx.x * 4) = o;
  } else {
    float4 o = { ox, oy, oz, ow };
    ((float4*)(outf + (size_t)row * DM))[threadIdx.x] = o;
  }
}

// ---------------- f16 MFMA GEMM: C[m,n] = sum_k A[m,k]*B[n,k] ----------------
// 128x128 tile, BK=32, 256 threads (4 waves, 2x2 of 64x64), global_load_lds staging
template <int BIAS, int RELU, int RESID, int OUTF16>
__global__ __launch_bounds__(256) void gemm_mfma(
    const _Float16* __restrict__ A, const _Float16* __restrict__ B,
    const float* __restrict__ bias, const float* __restrict__ resid,
    float* __restrict__ Cf, _Float16* __restrict__ Ch,
    int M, int N, int K) {
  __shared__ alignas(16) _Float16 As[128 * 32];
  __shared__ alignas(16) _Float16 Bs[128 * 32];
  const int t = threadIdx.x;
  const int lane = t & 63, wid = t >> 6;
  const int m0 = blockIdx.y * 128, n0 = blockIdx.x * 128;
  const int wm = (wid >> 1) * 64, wn = (wid & 1) * 64;

  const int c0 = wid * 64 + lane, c1 = c0 + 256;
  const _Float16* Ap0 = A + (size_t)(m0 + (c0 >> 2)) * K + (c0 & 3) * 8;
  const _Float16* Ap1 = A + (size_t)(m0 + (c1 >> 2)) * K + (c1 & 3) * 8;
  const _Float16* Bp0 = B + (size_t)(n0 + (c0 >> 2)) * K + (c0 & 3) * 8;
  const _Float16* Bp1 = B + (size_t)(n0 + (c1 >> 2)) * K + (c1 & 3) * 8;
  _Float16* Asw0 = &As[wid * 512];
  _Float16* Asw1 = &As[wid * 512 + 2048];
  _Float16* Bsw0 = &Bs[wid * 512];
  _Float16* Bsw1 = &Bs[wid * 512 + 2048];

  f32x4 acc[4][4] = {};
  for (int k0 = 0; k0 < K; k0 += 32) {
    __syncthreads();
    gload16(Ap0 + k0, Asw0);
    gload16(Ap1 + k0, Asw1);
    gload16(Bp0 + k0, Bsw0);
    gload16(Bp1 + k0, Bsw1);
    __syncthreads();
    f16x8 af[4], bf[4];
#pragma unroll
    for (int f = 0; f < 4; ++f) {
      af[f] = *(const f16x8*)&As[(wm + f * 16 + (lane & 15)) * 32 + (lane >> 4) * 8];
      bf[f] = *(const f16x8*)&Bs[(wn + f * 16 + (lane & 15)) * 32 + (lane >> 4) * 8];
    }
#pragma unroll
    for (int i = 0; i < 4; ++i)
#pragma unroll
      for (int j = 0; j < 4; ++j)
        acc[i][j] = __builtin_amdgcn_mfma_f32_16x16x32_f16(af[i], bf[j], acc[i][j], 0, 0, 0);
  }
#pragma unroll
  for (int i = 0; i < 4; ++i) {
#pragma unroll
    for (int j = 0; j < 4; ++j) {
      const int n = n0 + wn + j * 16 + (lane & 15);
      float bv = 0.0f;
      if (BIAS) bv = bias[n];
#pragma unroll
      for (int r = 0; r < 4; ++r) {
        const int m = m0 + wm + i * 16 + (lane >> 4) * 4 + r;
        float v = acc[i][j][r] + bv;
        if (RELU) v = fmaxf(v, 0.0f);
        if (RESID) v += resid[(size_t)m * N + n];
        if (OUTF16) Ch[(size_t)m * N + n] = (_Float16)v;
        else        Cf[(size_t)m * N + n] = v;
      }
    }
  }
}

// ---------------- split-K GEMM: partial[z][m][n] = sum_{k in slice z} A[m,k]B[n,k] ----
__global__ __launch_bounds__(256) void gemm_sk(
    const _Float16* __restrict__ A, const _Float16* __restrict__ B,
    _Float16* __restrict__ pk, int M, int N, int K, int Ks) {
  __shared__ alignas(16) _Float16 As[128 * 32];
  __shared__ alignas(16) _Float16 Bs[128 * 32];
  const int t = threadIdx.x;
  const int lane = t & 63, wid = t >> 6;
  const int m0 = blockIdx.y * 128, n0 = blockIdx.x * 128;
  const int z = blockIdx.z;
  const int kbase = z * Ks;
  const int wm = (wid >> 1) * 64, wn = (wid & 1) * 64;

  const int c0 = wid * 64 + lane, c1 = c0 + 256;
  const _Float16* Ap0 = A + (size_t)(m0 + (c0 >> 2)) * K + kbase + (c0 & 3) * 8;
  const _Float16* Ap1 = A + (size_t)(m0 + (c1 >> 2)) * K + kbase + (c1 & 3) * 8;
  const _Float16* Bp0 = B + (size_t)(n0 + (c0 >> 2)) * K + kbase + (c0 & 3) * 8;
  const _Float16* Bp1 = B + (size_t)(n0 + (c1 >> 2)) * K + kbase + (c1 & 3) * 8;
  _Float16* Asw0 = &As[wid * 512];
  _Float16* Asw1 = &As[wid * 512 + 2048];
  _Float16* Bsw0 = &Bs[wid * 512];
  _Float16* Bsw1 = &Bs[wid * 512 + 2048];

  f32x4 acc[4][4] = {};
  for (int k0 = 0; k0 < Ks; k0 += 32) {
    __syncthreads();
    gload16(Ap0 + k0, Asw0);
    gload16(Ap1 + k0, Asw1);
    gload16(Bp0 + k0, Bsw0);
    gload16(Bp1 + k0, Bsw1);
    __syncthreads();
    f16x8 af[4], bf[4];
#pragma unroll
    for (int f = 0; f < 4; ++f) {
      af[f] = *(const f16x8*)&As[(wm + f * 16 + (lane & 15)) * 32 + (lane >> 4) * 8];
      bf[f] = *(const f16x8*)&Bs[(wn + f * 16 + (lane & 15)) * 32 + (lane >> 4) * 8];
    }
#pragma unroll
    for (int i = 0; i < 4; ++i)
#pragma unroll
      for (int j = 0; j < 4; ++j)
        acc[i][j] = __builtin_amdgcn_mfma_f32_16x16x32_f16(af[i], bf[j], acc[i][j], 0, 0, 0);
  }
  _Float16* out = pk + (size_t)z * M * N;
#pragma unroll
  for (int i = 0; i < 4; ++i)
#pragma unroll
    for (int j = 0; j < 4; ++j) {
      const int n = n0 + wn + j * 16 + (lane & 15);
#pragma unroll
      for (int r = 0; r < 4; ++r) {
        const int m = m0 + wm + i * 16 + (lane >> 4) * 4 + r;
        out[(size_t)m * N + n] = (_Float16)acc[i][j][r];
      }
    }
}

// ---------------- split-K reduce: C = sum_z pk[z] (+bias)(relu)(+resid) ----------------
template <int SK, int BIAS, int RELU, int RESID, int OUTF16>
__global__ __launch_bounds__(256) void reduce_k(
    const _Float16* __restrict__ pk, const float* __restrict__ bias,
    const float* __restrict__ resid, float* __restrict__ Cf,
    _Float16* __restrict__ Ch, int MN, int Nmask) {
  const int idx = (blockIdx.x * 256 + threadIdx.x) * 8;
  float s[8] = {};
#pragma unroll
  for (int zz = 0; zz < SK; ++zz) {
    f16x8 v = *(const f16x8*)(pk + (size_t)zz * MN + idx);
#pragma unroll
    for (int e = 0; e < 8; ++e) s[e] += (float)v[e];
  }
  if (BIAS) {
    const int n0 = idx & Nmask;
#pragma unroll
    for (int e = 0; e < 8; ++e) s[e] += bias[n0 + e];
  }
  if (RELU)
#pragma unroll
    for (int e = 0; e < 8; ++e) s[e] = fmaxf(s[e], 0.0f);
  if (RESID) {
    float4 r0 = *(const float4*)(resid + idx);
    float4 r1 = *(const float4*)(resid + idx + 4);
    s[0] += r0.x; s[1] += r0.y; s[2] += r0.z; s[3] += r0.w;
    s[4] += r1.x; s[5] += r1.y; s[6] += r1.z; s[7] += r1.w;
  }
  if (OUTF16) {
    f16x8 o;
#pragma unroll
    for (int e = 0; e < 8; ++e) o[e] = (_Float16)s[e];
    *(f16x8*)(Ch + idx) = o;
  } else {
    float4 o0 = { s[0], s[1], s[2], s[3] };
    float4 o1 = { s[4], s[5], s[6], s[7] };
    *(float4*)(Cf + idx) = o0;
    *(float4*)(Cf + idx + 4) = o1;
  }
}

// ---------------- MFMA flash relative attention, KV-split x2 ----------------
// grid (8 q-tiles, 16 heads, 8 = batch + 4*z); 256 threads = 4 waves x 16 q-rows.
// Block z handles key-tiles t = z, z+2, ... Outputs normalized partial O (f16)
// plus per-row (m, l) in log2 domain for the combine pass.
__global__ __launch_bounds__(256, 4) void attn_kernel(
    const _Float16* __restrict__ wh,  // (KL*B_, 3072) f16 qkv projections
    const _Float16* __restrict__ rk,  // (KL, 1024) f16 r_head_k
    const float* __restrict__ rwb,    // (16,64)
    const float* __restrict__ rrb,    // (16,64)
    _Float16* __restrict__ po,        // [2][QLEN*B_*1024] partial O-hat
    float* __restrict__ pm,           // [2][32768] running max (log2 domain)
    float* __restrict__ pl) {         // [2][32768] running sum
  __shared__ alignas(16) _Float16 RR[128 * 72];  // R tile
  __shared__ alignas(16) _Float16 KS[64 * 72];   // K tile, union V^T [d][j]
  __shared__ alignas(16) _Float16 QS[64 * 72];   // shifted QR, union PS

  const int i0 = blockIdx.x * 64, n = blockIdx.y;
  const int b = blockIdx.z & 3, zz = blockIdx.z >> 2;
  const int t = threadIdx.x, lane = t & 63, wid = t >> 6;
  const int g = lane >> 4, li = lane & 15;
  const int strip = wid * 16;

  // ---- Q fragments (+biases) in registers: row = strip+li, k = ks*32+g*8 ----
  f16x8 qw[2], qr[2];
#pragma unroll
  for (int ks_ = 0; ks_ < 2; ++ks_) {
    const _Float16* qp =
        wh + ((size_t)(MLEN + i0 + strip + li) * B_ + b) * 3072 + n * 64 + ks_ * 32 + g * 8;
    f16x8 qv = *(const f16x8*)qp;
#pragma unroll
    for (int e = 0; e < 8; ++e) {
      float f0 = (float)qv[e];
      qw[ks_][e] = (_Float16)(f0 + rwb[n * 64 + ks_ * 32 + g * 8 + e]);
      qr[ks_][e] = (_Float16)(f0 + rrb[n * 64 + ks_ * 32 + g * 8 + e]);
    }
  }

  f32x4 o_[4] = {};
  float mrun[4], lrun[4];
#pragma unroll
  for (int r = 0; r < 4; ++r) { mrun[r] = -INFINITY; lrun[r] = 0.0f; }

  const float SC = 0.125f * 1.44269504f;  // scale * log2(e): softmax in base 2
  const int ntiles = i0 / 64 + 3;
  for (int tt = zz; tt < ntiles; tt += 2) {
    const int j0 = tt * 64;
    __syncthreads();  // prev PV reads of KS/QS done
    // ---- stage K tile ----
    {
      int row = t >> 2, c = (t & 3) * 16;
      const _Float16* kp = wh + ((size_t)(j0 + row) * B_ + b) * 3072 + 1024 + n * 64 + c;
      *(f16x8*)&KS[row * 72 + c] = *(const f16x8*)kp;
      *(f16x8*)&KS[row * 72 + c + 8] = *(const f16x8*)(kp + 8);
    }
    // ---- stage R tile (clamped rows are masked anyway) ----
    {
      int row = t >> 1, c = (t & 1) * 32;
      int mrow = j0 - i0 + 448 + row;
      if (mrow > KL - 1) mrow = KL - 1;
      const _Float16* rp = rk + (size_t)mrow * DM + n * 64 + c;
#pragma unroll
      for (int cc = 0; cc < 32; cc += 8)
        *(f16x8*)&RR[row * 72 + c + cc] = *(const f16x8*)(rp + cc);
    }
    __syncthreads();
    // ---- QK^T: 4 col-frags ----
    f32x4 acs[4] = {};
#pragma unroll
    for (int ks_ = 0; ks_ < 2; ++ks_)
#pragma unroll
      for (int cf = 0; cf < 4; ++cf) {
        f16x8 bk = *(const f16x8*)&KS[(cf * 16 + li) * 72 + ks_ * 32 + g * 8];
        acs[cf] = __builtin_amdgcn_mfma_f32_16x16x32_f16(qw[ks_], bk, acs[cf], 0, 0, 0);
      }
    // ---- QR in two halves of 4 frags; shifted store QS[il][jl] = QR[il][jl-il+63] ----
#pragma unroll
    for (int half = 0; half < 2; ++half) {
      f32x4 acq[4] = {};
#pragma unroll
      for (int ks_ = 0; ks_ < 2; ++ks_)
#pragma unroll
        for (int cf = 0; cf < 4; ++cf) {
          f16x8 br = *(const f16x8*)&RR[((half * 4 + cf) * 16 + li) * 72 + ks_ * 32 + g * 8];
          acq[cf] = __builtin_amdgcn_mfma_f32_16x16x32_f16(qr[ks_], br, acq[cf], 0, 0, 0);
        }
#pragma unroll
      for (int cf = 0; cf < 4; ++cf)
#pragma unroll
        for (int r = 0; r < 4; ++r) {
          int il = strip + g * 4 + r;
          int jl = (half * 4 + cf) * 16 + li - 63 + il;
          if ((unsigned)jl < 64u) QS[il * 72 + jl] = (_Float16)acq[cf][r];
        }
    }
    __syncthreads();
    // ---- online softmax (log2 domain) ----
    float pf[4][4], fac[4];
#pragma unroll
    for (int r = 0; r < 4; ++r) {
      int il = strip + g * 4 + r, gi = i0 + il;
      float sv[4], mx = -INFINITY;
#pragma unroll
      for (int cf = 0; cf < 4; ++cf) {
        int jl = cf * 16 + li;
        float v = (acs[cf][r] + (float)QS[il * 72 + jl]) * SC;
        if (j0 + jl > gi + MLEN) v = -INFINITY;
        sv[cf] = v;
        mx = fmaxf(mx, v);
      }
#pragma unroll
      for (int o2 = 1; o2 < 16; o2 <<= 1) mx = fmaxf(mx, __shfl_xor(mx, o2, 64));
      float mnew = fmaxf(mrun[r], mx);
      float fc = exp2f(mrun[r] - mnew);
      float sum = 0.0f;
#pragma unroll
      for (int cf = 0; cf < 4; ++cf) { pf[cf][r] = exp2f(sv[cf] - mnew); sum += pf[cf][r]; }
#pragma unroll
      for (int o2 = 1; o2 < 16; o2 <<= 1) sum += __shfl_xor(sum, o2, 64);
      lrun[r] = lrun[r] * fc + sum;
      mrun[r] = mnew;
      fac[r] = fc;
    }
    __syncthreads();  // QS reads done before P overwrite
    // ---- P -> QS, stage V^T into KS ----
#pragma unroll
    for (int cf = 0; cf < 4; ++cf)
#pragma unroll
      for (int r = 0; r < 4; ++r)
        QS[(strip + g * 4 + r) * 72 + cf * 16 + li] = (_Float16)pf[cf][r];
#pragma unroll
    for (int it = 0; it < 2; ++it) {
      int j = t & 63, d0 = (t >> 6) * 8 + it * 32;
      f16x8 vv = *(const f16x8*)(wh + ((size_t)(j0 + j) * B_ + b) * 3072 + 2048 + n * 64 + d0);
#pragma unroll
      for (int e = 0; e < 8; ++e) KS[(d0 + e) * 72 + j] = vv[e];
    }
    __syncthreads();
    // ---- PV: O = O*fac + P V ----
#pragma unroll
    for (int cf = 0; cf < 4; ++cf)
#pragma unroll
      for (int r = 0; r < 4; ++r)
        o_[cf][r] *= fac[r];
#pragma unroll
    for (int ks_ = 0; ks_ < 2; ++ks_) {
      f16x8 pa = *(const f16x8*)&QS[(strip + li) * 72 + ks_ * 32 + g * 8];
#pragma unroll
      for (int cf = 0; cf < 4; ++cf) {
        f16x8 bv = *(const f16x8*)&KS[(cf * 16 + li) * 72 + ks_ * 32 + g * 8];
        o_[cf] = __builtin_amdgcn_mfma_f32_16x16x32_f16(pa, bv, o_[cf], 0, 0, 0);
      }
    }
  }
  // ---- write normalized partial + (m, l) ----
  const size_t obase = (size_t)zz * (QLEN * B_ * 1024);
#pragma unroll
  for (int cf = 0; cf < 4; ++cf)
#pragma unroll
    for (int r = 0; r < 4; ++r) {
      int row = strip + g * 4 + r;
      float l = lrun[r];
      float oo = (l > 0.0f) ? o_[cf][r] / l : 0.0f;
      po[obase + ((size_t)(i0 + row) * B_ + b) * 1024 + n * 64 + cf * 16 + li] = (_Float16)oo;
    }
  if (li == 0) {
#pragma unroll
    for (int r = 0; r < 4; ++r) {
      int row = strip + g * 4 + r;
      int idx = ((i0 + row) * B_ + b) * 16 + n;
      pm[zz * 32768 + idx] = (lrun[r] > 0.0f) ? mrun[r] : -3.0e38f;
      pl[zz * 32768 + idx] = lrun[r];
    }
  }
}

// ---------------- combine the two KV-split halves ----------------
__global__ __launch_bounds__(256) void attn_combine(
    const _Float16* __restrict__ po, const float* __restrict__ pm,
    const float* __restrict__ pl, _Float16* __restrict__ av) {
  const size_t e = ((size_t)blockIdx.x * 256 + threadIdx.x) * 8;
  const int mlidx = (int)(e >> 10) * 16 + (((int)e & 1023) >> 6);
  float m1 = pm[mlidx], m2 = pm[32768 + mlidx];
  float l1 = pl[mlidx], l2 = pl[32768 + mlidx];
  float M = fmaxf(m1, m2);
  float w1 = l1 * exp2f(m1 - M), w2 = l2 * exp2f(m2 - M);
  float inv = 1.0f / (w1 + w2);
  w1 *= inv; w2 *= inv;
  f16x8 o1 = *(const f16x8*)(po + e);
  f16x8 o2 = *(const f16x8*)(po + 2097152 + e);
  f16x8 o;
#pragma unroll
  for (int k = 0; k < 8; ++k) o[k] = (_Float16)(w1 * (float)o1[k] + w2 * (float)o2[k]);
  *(f16x8*)(av + e) = o;
}

// ---------------- host ----------------
extern "C" void kernel_launch(void* const* d_in, const int* in_sizes, int n_in,
                              void* d_out, int out_size, void* d_ws, size_t ws_size,
                              hipStream_t stream) {
  const float* inputs = (const float*)d_in[0];
  const float* mems   = (const float*)d_in[1];
  const float* rwb    = (const float*)d_in[2];
  const float* rrb    = (const float*)d_in[3];
  const float* qkv_w  = (const float*)d_in[4];
  const float* r_w    = (const float*)d_in[5];
  const float* o_w    = (const float*)d_in[6];
  const float* ln1_g  = (const float*)d_in[7];
  const float* ln1_b  = (const float*)d_in[8];
  const float* ff_w1  = (const float*)d_in[9];
  const float* ff_b1  = (const float*)d_in[10];
  const float* ff_w2  = (const float*)d_in[11];
  const float* ff_b2  = (const float*)d_in[12];
  const float* ln2_g  = (const float*)d_in[13];
  const float* ln2_b  = (const float*)d_in[14];
  const float* fin_g  = (const float*)d_in[15];
  const float* fin_b  = (const float*)d_in[16];
  float* out = (float*)d_out;

  float* ws = (float*)d_ws;
  float* xbuf = ws;                               // 2,097,152 f32
  _Float16* fb = (_Float16*)(ws + 2097152);
  _Float16* wh_h  = fb;                           // 7,864,320
  _Float16* rk_h  = wh_h + 7864320;               //   655,360
  _Float16* pe_h  = rk_h + 655360;                //   655,360
  _Float16* h_h   = pe_h + 655360;                // 2,621,440
  _Float16* av_h  = h_h + 2621440;                // 2,097,152
  _Float16* ffh_h = av_h + 2097152;               // 8,388,608
  _Float16* wb_h  = ffh_h + 8388608;              // 13,631,488
  _Float16* wq = wb_h;
  _Float16* wr = wb_h + 3145728;
  _Float16* wo = wb_h + 4194304;
  _Float16* w1 = wb_h + 5242880;
  _Float16* w2 = wb_h + 9437184;
  // overlays on dead regions:
  _Float16* pk_big = wh_h;   // o-proj / ff2 split-K partials (wh dead post-attn)
  _Float16* pk_rk  = ffh_h;  // rk split-K partials (pre-attn)
  _Float16* po     = ffh_h;                    // 2 x 2,097,152 f16 attn partial O
  float*    pm     = (float*)(ffh_h + 4194304); // 2 x 32768 f32
  float*    pl     = pm + 65536;               // 2 x 32768 f32

  pos_emb_kernel<<<KL, 256, 0, stream>>>(pe_h);

  const float* xcur = inputs;
  for (int l = 0; l < NL; ++l) {
    cast_w_kernel<<<13312, 256, 0, stream>>>(
        qkv_w + (size_t)l * 3145728, r_w + (size_t)l * 1048576,
        o_w + (size_t)l * 1048576, ff_w1 + (size_t)l * 4194304,
        ff_w2 + (size_t)l * 4194304, wb_h);
    // LN over [mems_l ; x] -> h_h (2560 rows, f16)
    ln_kernel<1><<<KL * B_, 256, 0, stream>>>(
        mems + (size_t)l * MLEN * B_ * DM, xcur,
        ln1_g + l * DM, ln1_b + l * DM, nullptr, h_h, MLEN * B_);
    // QKV projection -> wh f16
    gemm_mfma<0, 0, 0, 1><<<dim3(3072 / 128, 2560 / 128), 256, 0, stream>>>(
        h_h, wq, nullptr, nullptr, nullptr, wh_h, 2560, 3072, DM);
    // r_head_k: split-K=8 -> reduce -> rk f16
    gemm_sk<<<dim3(DM / 128, KL / 128, 8), 256, 0, stream>>>(
        pe_h, wr, pk_rk, KL, DM, DM, DM / 8);
    reduce_k<8, 0, 0, 0, 1><<<KL * DM / 2048, 256, 0, stream>>>(
        pk_rk, nullptr, nullptr, nullptr, rk_h, KL * DM, DM - 1);
    // attention (KV-split x2) -> partials -> combine -> av_h
    attn_kernel<<<dim3(QLEN / 64, NH, B_ * 2), 256, 0, stream>>>(
        wh_h, rk_h, rwb, rrb, po, pm, pl);
    attn_combine<<<1024, 256, 0, stream>>>(po, pm, pl, av_h);
    // out projection: split-K=4 -> reduce(+resid) -> xbuf fp32
    gemm_sk<<<dim3(DM / 128, (QLEN * B_) / 128, 4), 256, 0, stream>>>(
        av_h, wo, pk_big, QLEN * B_, DM, DM, DM / 4);
    reduce_k<4, 0, 0, 1, 0><<<QLEN * B_ * DM / 2048, 256, 0, stream>>>(
        pk_big, nullptr, xcur, xbuf, nullptr, QLEN * B_ * DM, DM - 1);
    // FFN
    ln_kernel<1><<<QLEN * B_, 256, 0, stream>>>(
        xbuf, nullptr, ln2_g + l * DM, ln2_b + l * DM, nullptr, h_h, 1 << 30);
    gemm_mfma<1, 1, 0, 1><<<dim3(DFF / 128, (QLEN * B_) / 128), 256, 0, stream>>>(
        h_h, w1, ff_b1 + (size_t)l * DFF, nullptr, nullptr, ffh_h, QLEN * B_, DFF, DM);
    gemm_sk<<<dim3(DM / 128, (QLEN * B_) / 128, 4), 256, 0, stream>>>(
        ffh_h, w2, pk_big, QLEN * B_, DM, DFF, DFF / 4);
    reduce_k<4, 1, 0, 1, 0><<<QLEN * B_ * DM / 2048, 256, 0, stream>>>(
        pk_big, ff_b2 + (size_t)l * DM, xbuf, xbuf, nullptr, QLEN * B_ * DM, DM - 1);
    xcur = xbuf;
  }
  ln_kernel<0><<<QLEN * B_, 256, 0, stream>>>(xbuf, nullptr, fin_g, fin_b, out, nullptr, 1 << 30);
}